// Round 1
// baseline (590.211 us; speedup 1.0000x reference)
//
#include <hip/hip_runtime.h>

#define TC_L    1024
#define TC_K    64
#define TC_LN   128
#define TC_NCLS 10
#define TC_DCAT 8320

// ---------------------------------------------------------------------------
// K1: conv1  x[n,k,l] = sum_t w1[k,t] * X[n, l-4+t]   (pad 4)
// grid (k=64, n=64), 256 thr
__global__ __launch_bounds__(256) void k_conv1(
    const float* __restrict__ X, const float* __restrict__ w1, float* __restrict__ x)
{
    const int k = blockIdx.x, n = blockIdx.y;
    float w[9];
#pragma unroll
    for (int t = 0; t < 9; ++t) w[t] = w1[k * 9 + t];
    const float* xin = X + n * TC_L;
    float* out = x + (n * TC_K + k) * TC_L;
    for (int l = threadIdx.x; l < TC_L; l += 256) {
        float acc = 0.f;
#pragma unroll
        for (int t = 0; t < 9; ++t) {
            int idx = l - 4 + t;
            float v = (idx >= 0 && idx < TC_L) ? xin[idx] : 0.f;
            acc = fmaf(w[t], v, acc);
        }
        out[l] = acc;
    }
}

// ---------------------------------------------------------------------------
// K2: psi_m conv  xs[n,oc,l] = sum_{ic,t} w2[oc,ic,t] * x[n,ic,l-2+t]  (pad 2)
// grid (ocb=8, n=64), 256 thr, 8 oc per block, L chunked by 256
__global__ __launch_bounds__(256) void k_psim(
    const float* __restrict__ x, const float* __restrict__ w2, float* __restrict__ xs)
{
    const int ocb = blockIdx.x;
    const int n = blockIdx.y;
    __shared__ float wl[8 * 320];     // 10 KB
    __shared__ float xl[64][260];     // 66.6 KB
    const int tid = threadIdx.x;
    for (int i = tid; i < 8 * 320; i += 256) wl[i] = w2[ocb * 8 * 320 + i];

    const int lgrp = tid & 63;        // 0..63 -> l0 = lgrp*4
    const int ocg  = tid >> 6;        // 0..3  -> oc pair base = ocg*2
    const int l0 = lgrp * 4;
    const int oc0 = ocg * 2;

    for (int lc = 0; lc < TC_L; lc += 256) {
        __syncthreads();
        for (int i = tid; i < 64 * 260; i += 256) {
            int ic = i / 260, d = i - ic * 260;
            int gl = lc - 2 + d;
            xl[ic][d] = (gl >= 0 && gl < TC_L) ? x[(n * TC_K + ic) * TC_L + gl] : 0.f;
        }
        __syncthreads();
        float acc[2][4] = {};
        for (int ic = 0; ic < 64; ++ic) {
            float4 va = *(const float4*)&xl[ic][l0];
            float4 vb = *(const float4*)&xl[ic][l0 + 4];
            float v[8] = {va.x, va.y, va.z, va.w, vb.x, vb.y, vb.z, vb.w};
            const float* wp0 = &wl[(oc0 + 0) * 320 + ic * 5];
            const float* wp1 = &wl[(oc0 + 1) * 320 + ic * 5];
#pragma unroll
            for (int t = 0; t < 5; ++t) {
                float w0 = wp0[t], w1 = wp1[t];
#pragma unroll
                for (int j = 0; j < 4; ++j) {
                    acc[0][j] = fmaf(w0, v[j + t], acc[0][j]);
                    acc[1][j] = fmaf(w1, v[j + t], acc[1][j]);
                }
            }
        }
#pragma unroll
        for (int q = 0; q < 2; ++q) {
            int oc = ocb * 8 + oc0 + q;
            *(float4*)&xs[(n * TC_K + oc) * TC_L + lc + l0] =
                make_float4(acc[q][0], acc[q][1], acc[q][2], acc[q][3]);
        }
    }
}

// ---------------------------------------------------------------------------
// K3: squash each row of 1024 in place:  v *= sq/((1+sq)(sq+1e-8)), sq = sum v^2
// grid (4096), 256 thr
__global__ __launch_bounds__(256) void k_squash_rows(float* __restrict__ xs)
{
    const int row = blockIdx.x;
    float* p = xs + (size_t)row * TC_L;
    const int tid = threadIdx.x;
    float4 v = *(const float4*)&p[tid * 4];
    float part = v.x * v.x + v.y * v.y + v.z * v.z + v.w * v.w;
    __shared__ float red[256];
    red[tid] = part;
    __syncthreads();
    for (int s = 128; s > 0; s >>= 1) {
        if (tid < s) red[tid] += red[tid + s];
        __syncthreads();
    }
    float sq = red[0];
    float scale = sq / ((1.f + sq) * (sq + 1e-8f));
    v.x *= scale; v.y *= scale; v.z *= scale; v.w *= scale;
    *(float4*)&p[tid * 4] = v;
}

// ---------------------------------------------------------------------------
// K5a: Cell_B convs + bias + squash(last=128) -> xbS[n][j=8][s=8][128]
// grid (s=8, n=64), 256 thr
__global__ __launch_bounds__(256) void k_cellB_conv(
    const float* __restrict__ x, const float* __restrict__ wB, const float* __restrict__ bB,
    const float* __restrict__ wk, const float* __restrict__ bk, float* __restrict__ xbS)
{
    const int s = blockIdx.x;
    const int n = blockIdx.y;
    __shared__ float wBl[64 * 64];    // 16 KB
    __shared__ float wkl[8 * 320];    // 10 KB
    __shared__ float xb1[64][132];    // 33.8 KB  (2-elem zero halo each side)
    __shared__ float redq[8][33];
    const int tid = threadIdx.x;
    for (int i = tid; i < 4096; i += 256) wBl[i] = wB[i];
    for (int i = tid; i < 2560; i += 256) wkl[i] = wk[i];
    for (int i = tid; i < 64; i += 256) {
        xb1[i][0] = xb1[i][1] = xb1[i][130] = xb1[i][131] = 0.f;
    }
    __syncthreads();

    // step 1: xb1[ch][t] = bB[ch] + sum_k wB[ch][k] * x[n][k][s*128+t]
    {
        const int t0  = (tid & 31) * 4;   // 0..124
        const int chg = tid >> 5;         // 0..7  -> ch = chg*8 + cc
        float acc[8][4] = {};
        const float* xbase = x + (size_t)n * TC_K * TC_L + s * TC_LN + t0;
        for (int k = 0; k < 64; ++k) {
            float4 xv = *(const float4*)&xbase[(size_t)k * TC_L];
            float v0 = xv.x, v1 = xv.y, v2 = xv.z, v3 = xv.w;
#pragma unroll
            for (int cc = 0; cc < 8; ++cc) {
                float w = wBl[(chg * 8 + cc) * 64 + k];
                acc[cc][0] = fmaf(w, v0, acc[cc][0]);
                acc[cc][1] = fmaf(w, v1, acc[cc][1]);
                acc[cc][2] = fmaf(w, v2, acc[cc][2]);
                acc[cc][3] = fmaf(w, v3, acc[cc][3]);
            }
        }
#pragma unroll
        for (int cc = 0; cc < 8; ++cc) {
            int ch = chg * 8 + cc;
            float b = bB[ch];
            xb1[ch][2 + t0 + 0] = acc[cc][0] + b;
            xb1[ch][2 + t0 + 1] = acc[cc][1] + b;
            xb1[ch][2 + t0 + 2] = acc[cc][2] + b;
            xb1[ch][2 + t0 + 3] = acc[cc][3] + b;
        }
    }
    __syncthreads();

    // step 2: xbB[j][t] = bk[j] + sum_{ch,dw} wk[j,ch,dw]*xb1[ch][t-2+dw]; squash over t
    {
        const int t0 = (tid & 31) * 4;
        const int j  = tid >> 5;          // 0..7
        float acc[4] = {};
        for (int ch = 0; ch < 64; ++ch) {
            float4 va = *(const float4*)&xb1[ch][t0];
            float4 vb = *(const float4*)&xb1[ch][t0 + 4];
            float v[8] = {va.x, va.y, va.z, va.w, vb.x, vb.y, vb.z, vb.w};
            const float* wp = &wkl[j * 320 + ch * 5];
#pragma unroll
            for (int dw = 0; dw < 5; ++dw) {
                float w = wp[dw];
#pragma unroll
                for (int q = 0; q < 4; ++q) acc[q] = fmaf(w, v[q + dw], acc[q]);
            }
        }
        float b = bk[j];
#pragma unroll
        for (int q = 0; q < 4; ++q) acc[q] += b;
        float part = acc[0]*acc[0] + acc[1]*acc[1] + acc[2]*acc[2] + acc[3]*acc[3];
        redq[j][tid & 31] = part;
        __syncthreads();
        for (int st = 16; st > 0; st >>= 1) {
            if ((tid & 31) < st) redq[j][tid & 31] += redq[j][(tid & 31) + st];
            __syncthreads();
        }
        float sq = redq[j][0];
        float scale = sq / ((1.f + sq) * (sq + 1e-8f));
        float* outp = xbS + (((size_t)n * 8 + j) * 8 + s) * TC_LN + t0;
        *(float4*)outp = make_float4(acc[0]*scale, acc[1]*scale, acc[2]*scale, acc[3]*scale);
    }
}

// ---------------------------------------------------------------------------
// K5b: routing over s for Cell_B -> xB[n][j][t]
// grid (j=8, n=64), 128 thr
__global__ __launch_bounds__(128) void k_routeB(
    const float* __restrict__ xbS, float* __restrict__ xB)
{
    const int j = blockIdx.x, n = blockIdx.y;
    const int t = threadIdx.x;
    float xv[8];
    const float* base = xbS + ((size_t)n * 8 + j) * 8 * TC_LN;
#pragma unroll
    for (int s = 0; s < 8; ++s) xv[s] = base[s * TC_LN + t];

    __shared__ float red[128];
    __shared__ float redp[8][129];

    // iter 1 (c uniform 1/8)
    float sj = 0.f;
#pragma unroll
    for (int s = 0; s < 8; ++s) sj += xv[s];
    sj *= 0.125f;
    red[t] = sj * sj;
    __syncthreads();
    for (int st = 64; st > 0; st >>= 1) { if (t < st) red[t] += red[t + st]; __syncthreads(); }
    float sq = red[0];
    float vfac = sq / ((1.f + sq) * (sq + 1e-8f));
    float vj = vfac * sj;
#pragma unroll
    for (int s = 0; s < 8; ++s) redp[s][t] = xv[s] * vj;
    __syncthreads();
    for (int st = 64; st > 0; st >>= 1) {
        if (t < st) {
#pragma unroll
            for (int s = 0; s < 8; ++s) redp[s][t] += redp[s][t + st];
        }
        __syncthreads();
    }
    float bv[8], bmax = -1e30f;
#pragma unroll
    for (int s = 0; s < 8; ++s) { bv[s] = redp[s][0]; bmax = fmaxf(bmax, bv[s]); }
    float esum = 0.f;
#pragma unroll
    for (int s = 0; s < 8; ++s) { bv[s] = __expf(bv[s] - bmax); esum += bv[s]; }
    float cinv = 1.f / esum;
    // iter 2
    float sj2 = 0.f;
#pragma unroll
    for (int s = 0; s < 8; ++s) sj2 += bv[s] * xv[s];
    sj2 *= cinv;
    __syncthreads();
    red[t] = sj2 * sj2;
    __syncthreads();
    for (int st = 64; st > 0; st >>= 1) { if (t < st) red[t] += red[t + st]; __syncthreads(); }
    float sq2 = red[0];
    float vfac2 = sq2 / ((1.f + sq2) * (sq2 + 1e-8f));
    xB[((size_t)n * 8 + j) * TC_LN + t] = vfac2 * sj2;
}

// ---------------------------------------------------------------------------
// K4: Cell_A conv2d (8x3, stride 8 over caps) + bias + routing over p -> vjA[n][o][l]
// grid (o=64, n=64), 256 thr; conv outputs kept in registers (thread owns all p for its l-strip)
__global__ __launch_bounds__(256) void k_cellA(
    const float* __restrict__ xs, const float* __restrict__ wA, const float* __restrict__ bA,
    float* __restrict__ vjA)
{
    const int o = blockIdx.x;
    const int n = blockIdx.y;
    const int tid = threadIdx.x;
    const int l0 = tid * 4;

    float w[24];
#pragma unroll
    for (int i = 0; i < 24; ++i) w[i] = wA[o * 24 + i];
    const float bias = bA[o];

    const float* xsn = xs + (size_t)n * TC_K * TC_L;
    float xrv[8][4];
#pragma unroll
    for (int p = 0; p < 8; ++p) {
        float acc[4] = {bias, bias, bias, bias};
#pragma unroll
        for (int dh = 0; dh < 8; ++dh) {
            const float* row = xsn + (p * 8 + dh) * TC_L;
            float4 vm = *(const float4*)&row[l0];
            float v[6];
            v[0] = (l0 > 0) ? row[l0 - 1] : 0.f;
            v[1] = vm.x; v[2] = vm.y; v[3] = vm.z; v[4] = vm.w;
            v[5] = (l0 + 4 < TC_L) ? row[l0 + 4] : 0.f;
#pragma unroll
            for (int dw = 0; dw < 3; ++dw) {
                float wv = w[dh * 3 + dw];
#pragma unroll
                for (int jj = 0; jj < 4; ++jj)
                    acc[jj] = fmaf(wv, v[jj + dw], acc[jj]);
            }
        }
#pragma unroll
        for (int jj = 0; jj < 4; ++jj) xrv[p][jj] = acc[jj];
    }

    __shared__ float red[256];
    __shared__ float redp[8][257];

    // routing iter 1
    float sjv[4];
    float part = 0.f;
#pragma unroll
    for (int jj = 0; jj < 4; ++jj) {
        float sv = 0.f;
#pragma unroll
        for (int p = 0; p < 8; ++p) sv += xrv[p][jj];
        sv *= 0.125f;
        sjv[jj] = sv;
        part += sv * sv;
    }
    red[tid] = part;
    __syncthreads();
    for (int st = 128; st > 0; st >>= 1) { if (tid < st) red[tid] += red[tid + st]; __syncthreads(); }
    float sq = red[0];
    float vfac = sq / ((1.f + sq) * (sq + 1e-8f));
    float bp[8] = {};
#pragma unroll
    for (int jj = 0; jj < 4; ++jj) {
        float vj = vfac * sjv[jj];
#pragma unroll
        for (int p = 0; p < 8; ++p) bp[p] += xrv[p][jj] * vj;
    }
#pragma unroll
    for (int p = 0; p < 8; ++p) redp[p][tid] = bp[p];
    __syncthreads();
    for (int st = 128; st > 0; st >>= 1) {
        if (tid < st) {
#pragma unroll
            for (int p = 0; p < 8; ++p) redp[p][tid] += redp[p][tid + st];
        }
        __syncthreads();
    }
    float bv[8], bmax = -1e30f;
#pragma unroll
    for (int p = 0; p < 8; ++p) { bv[p] = redp[p][0]; bmax = fmaxf(bmax, bv[p]); }
    float esum = 0.f;
#pragma unroll
    for (int p = 0; p < 8; ++p) { bv[p] = __expf(bv[p] - bmax); esum += bv[p]; }
    float cinv = 1.f / esum;
    // iter 2
    float sj2[4]; float part2 = 0.f;
#pragma unroll
    for (int jj = 0; jj < 4; ++jj) {
        float sv = 0.f;
#pragma unroll
        for (int p = 0; p < 8; ++p) sv += bv[p] * xrv[p][jj];
        sv *= cinv;
        sj2[jj] = sv;
        part2 += sv * sv;
    }
    __syncthreads();
    red[tid] = part2;
    __syncthreads();
    for (int st = 128; st > 0; st >>= 1) { if (tid < st) red[tid] += red[tid + st]; __syncthreads(); }
    float sq2 = red[0];
    float vfac2 = sq2 / ((1.f + sq2) * (sq2 + 1e-8f));
    float* outp = vjA + ((size_t)n * 64 + o) * TC_L + l0;
    *(float4*)outp = make_float4(vfac2*sj2[0], vfac2*sj2[1], vfac2*sj2[2], vfac2*sj2[3]);
}

// ---------------------------------------------------------------------------
// K6: DigitCaps u[c,o] = sum_d xcat[c,d]*W[k,d,o] + routing over c -> out[n,k,o]
// grid (kcls=10, n=64), 256 thr (= 16 o x 16 d-lanes)
__global__ __launch_bounds__(256) void k_digit(
    const float* __restrict__ vjA, const float* __restrict__ xB,
    const float* __restrict__ W, const float* __restrict__ alphap,
    const float* __restrict__ betap, float* __restrict__ out)
{
    const int kc = blockIdx.x;
    const int n = blockIdx.y;
    const int tid = threadIdx.x;
    const int o  = tid & 15;
    const int dl = tid >> 4;     // 0..15
    const float alpha = alphap[0], beta = betap[0];

    __shared__ float xT[512][8];     // 16 KB, [dd][c]
    float acc[8] = {};

    const float* vjAn = vjA + (size_t)n * 65536;
    const float* xBn  = xB  + (size_t)n * 1024;
    const float* Wk   = W   + (size_t)kc * (TC_DCAT * 16);

    for (int d0 = 0; d0 < TC_DCAT; d0 += 512) {
        __syncthreads();
        for (int i = tid; i < 512 * 8; i += 256) {
            int c = i >> 9;
            int dd = i & 511;
            int d = d0 + dd;
            float v = 0.f;
            if (d < 8192) v = alpha * vjAn[c * 8192 + d];
            else if (d < TC_DCAT) v = beta * xBn[c * 128 + (d - 8192)];
            xT[dd][c] = v;
        }
        __syncthreads();
#pragma unroll 4
        for (int i = 0; i < 32; ++i) {
            int d = dl + i * 16;
            int gd = d0 + d;
            int cl = gd < TC_DCAT ? gd : (TC_DCAT - 1);
            float wv = Wk[cl * 16 + o];
            float4 xa = *(const float4*)&xT[d][0];
            float4 xb = *(const float4*)&xT[d][4];
            acc[0] = fmaf(wv, xa.x, acc[0]);
            acc[1] = fmaf(wv, xa.y, acc[1]);
            acc[2] = fmaf(wv, xa.z, acc[2]);
            acc[3] = fmaf(wv, xa.w, acc[3]);
            acc[4] = fmaf(wv, xb.x, acc[4]);
            acc[5] = fmaf(wv, xb.y, acc[5]);
            acc[6] = fmaf(wv, xb.z, acc[6]);
            acc[7] = fmaf(wv, xb.w, acc[7]);
        }
    }

    __shared__ float redu[16][8][17];
#pragma unroll
    for (int c = 0; c < 8; ++c) redu[dl][c][o] = acc[c];
    __syncthreads();
    __shared__ float ul[8][16];
    if (tid < 128) {
        int c = tid >> 4, oo = tid & 15;
        float sv = 0.f;
#pragma unroll
        for (int q = 0; q < 16; ++q) sv += redu[q][c][oo];
        ul[c][oo] = sv;
    }
    __syncthreads();

    __shared__ float sjo[16];
    __shared__ float bc[8];
    __shared__ float fac[1];
    // routing iter 1
    if (tid < 16) {
        float sv = 0.f;
#pragma unroll
        for (int c = 0; c < 8; ++c) sv += ul[c][tid];
        sjo[tid] = sv * 0.125f;
    }
    __syncthreads();
    if (tid == 0) {
        float sq = 0.f;
#pragma unroll
        for (int oo = 0; oo < 16; ++oo) sq += sjo[oo] * sjo[oo];
        fac[0] = sq / ((1.f + sq) * (sq + 1e-8f));
    }
    __syncthreads();
    if (tid < 8) {
        float vf = fac[0];
        float sv = 0.f;
#pragma unroll
        for (int oo = 0; oo < 16; ++oo) sv += ul[tid][oo] * (vf * sjo[oo]);
        bc[tid] = sv;
    }
    __syncthreads();
    // iter 2
    if (tid < 16) {
        float bmax = -1e30f;
#pragma unroll
        for (int c = 0; c < 8; ++c) bmax = fmaxf(bmax, bc[c]);
        float e[8]; float es = 0.f;
#pragma unroll
        for (int c = 0; c < 8; ++c) { e[c] = __expf(bc[c] - bmax); es += e[c]; }
        float inv = 1.f / es;
        float sv = 0.f;
#pragma unroll
        for (int c = 0; c < 8; ++c) sv += e[c] * inv * ul[c][tid];
        sjo[tid] = sv;
    }
    __syncthreads();
    if (tid == 0) {
        float sq = 0.f;
#pragma unroll
        for (int oo = 0; oo < 16; ++oo) sq += sjo[oo] * sjo[oo];
        fac[0] = sq / ((1.f + sq) * (sq + 1e-8f));
    }
    __syncthreads();
    if (tid < 16) {
        out[((size_t)n * TC_NCLS + kc) * 16 + tid] = fac[0] * sjo[tid];
    }
}

// ---------------------------------------------------------------------------
extern "C" void kernel_launch(void* const* d_in, const int* in_sizes, int n_in,
                              void* d_out, int out_size, void* d_ws, size_t ws_size,
                              hipStream_t stream) {
    const float* X   = (const float*)d_in[0];
    const float* w1  = (const float*)d_in[1];
    const float* w2  = (const float*)d_in[2];
    const float* wA  = (const float*)d_in[3];
    const float* bA  = (const float*)d_in[4];
    const float* wB  = (const float*)d_in[5];
    const float* bB  = (const float*)d_in[6];
    const float* wk  = (const float*)d_in[7];
    const float* bk  = (const float*)d_in[8];
    const float* Wd  = (const float*)d_in[9];
    const float* alphap = (const float*)d_in[10];
    const float* betap  = (const float*)d_in[11];
    float* out = (float*)d_out;

    float* ws  = (float*)d_ws;
    float* x   = ws;                 // [64][64][1024] conv1 out; reused as vjA after Cell_B conv
    float* xs  = ws + 4194304;       // [64][64][1024] psi_m out, squashed in place
    float* xbS = ws + 8388608;       // [64][8][8][128]
    float* xB  = ws + 8912896;       // [64][8][128]
    float* vjA = x;                  // alias (x dead after k_cellB_conv)

    k_conv1<<<dim3(64, 64), 256, 0, stream>>>(X, w1, x);
    k_psim<<<dim3(8, 64), 256, 0, stream>>>(x, w2, xs);
    k_squash_rows<<<dim3(4096), 256, 0, stream>>>(xs);
    k_cellB_conv<<<dim3(8, 64), 256, 0, stream>>>(x, wB, bB, wk, bk, xbS);
    k_routeB<<<dim3(8, 64), 128, 0, stream>>>(xbS, xB);
    k_cellA<<<dim3(64, 64), 256, 0, stream>>>(xs, wA, bA, vjA);
    k_digit<<<dim3(10, 64), 256, 0, stream>>>(vjA, xB, Wd, alphap, betap, out);
}

// Round 2
// 503.767 us; speedup vs baseline: 1.1716x; 1.1716x over previous
//
#include <hip/hip_runtime.h>

#define TC_L    1024
#define TC_K    64
#define TC_LN   128
#define TC_NCLS 10
#define TC_DCAT 8320

// ---------------------------------------------------------------------------
// K1: conv1  x[n,k,l] = sum_t w1[k,t] * X[n, l-4+t]   (pad 4)
// grid (k=64, n=64), 256 thr
__global__ __launch_bounds__(256) void k_conv1(
    const float* __restrict__ X, const float* __restrict__ w1, float* __restrict__ x)
{
    const int k = blockIdx.x, n = blockIdx.y;
    float w[9];
#pragma unroll
    for (int t = 0; t < 9; ++t) w[t] = w1[k * 9 + t];
    const float* xin = X + n * TC_L;
    float* out = x + (n * TC_K + k) * TC_L;
    for (int l = threadIdx.x; l < TC_L; l += 256) {
        float acc = 0.f;
#pragma unroll
        for (int t = 0; t < 9; ++t) {
            int idx = l - 4 + t;
            float v = (idx >= 0 && idx < TC_L) ? xin[idx] : 0.f;
            acc = fmaf(w[t], v, acc);
        }
        out[l] = acc;
    }
}

// ---------------------------------------------------------------------------
// K2: psi_m conv  xs[n,oc,l] = sum_{ic,t} w2[oc,ic,t] * x[n,ic,l-2+t]  (pad 2)
// grid (ocb=8, n=64), 256 thr, 8 oc per block, L chunked by 256
__global__ __launch_bounds__(256) void k_psim(
    const float* __restrict__ x, const float* __restrict__ w2, float* __restrict__ xs)
{
    const int ocb = blockIdx.x;
    const int n = blockIdx.y;
    __shared__ float wl[8 * 320];     // 10 KB
    __shared__ float xl[64][260];     // 66.6 KB
    const int tid = threadIdx.x;
    for (int i = tid; i < 8 * 320; i += 256) wl[i] = w2[ocb * 8 * 320 + i];

    const int lgrp = tid & 63;        // 0..63 -> l0 = lgrp*4
    const int ocg  = tid >> 6;        // 0..3  -> oc pair base = ocg*2
    const int l0 = lgrp * 4;
    const int oc0 = ocg * 2;

    for (int lc = 0; lc < TC_L; lc += 256) {
        __syncthreads();
        for (int i = tid; i < 64 * 260; i += 256) {
            int ic = i / 260, d = i - ic * 260;
            int gl = lc - 2 + d;
            xl[ic][d] = (gl >= 0 && gl < TC_L) ? x[(n * TC_K + ic) * TC_L + gl] : 0.f;
        }
        __syncthreads();
        float acc[2][4] = {};
        for (int ic = 0; ic < 64; ++ic) {
            float4 va = *(const float4*)&xl[ic][l0];
            float4 vb = *(const float4*)&xl[ic][l0 + 4];
            float v[8] = {va.x, va.y, va.z, va.w, vb.x, vb.y, vb.z, vb.w};
            const float* wp0 = &wl[(oc0 + 0) * 320 + ic * 5];
            const float* wp1 = &wl[(oc0 + 1) * 320 + ic * 5];
#pragma unroll
            for (int t = 0; t < 5; ++t) {
                float w0 = wp0[t], w1 = wp1[t];
#pragma unroll
                for (int j = 0; j < 4; ++j) {
                    acc[0][j] = fmaf(w0, v[j + t], acc[0][j]);
                    acc[1][j] = fmaf(w1, v[j + t], acc[1][j]);
                }
            }
        }
#pragma unroll
        for (int q = 0; q < 2; ++q) {
            int oc = ocb * 8 + oc0 + q;
            *(float4*)&xs[(n * TC_K + oc) * TC_L + lc + l0] =
                make_float4(acc[q][0], acc[q][1], acc[q][2], acc[q][3]);
        }
    }
}

// ---------------------------------------------------------------------------
// K3: squash each row of 1024 in place:  v *= sq/((1+sq)(sq+1e-8)), sq = sum v^2
// grid (4096), 256 thr
__global__ __launch_bounds__(256) void k_squash_rows(float* __restrict__ xs)
{
    const int row = blockIdx.x;
    float* p = xs + (size_t)row * TC_L;
    const int tid = threadIdx.x;
    float4 v = *(const float4*)&p[tid * 4];
    float part = v.x * v.x + v.y * v.y + v.z * v.z + v.w * v.w;
    __shared__ float red[256];
    red[tid] = part;
    __syncthreads();
    for (int s = 128; s > 0; s >>= 1) {
        if (tid < s) red[tid] += red[tid + s];
        __syncthreads();
    }
    float sq = red[0];
    float scale = sq / ((1.f + sq) * (sq + 1e-8f));
    v.x *= scale; v.y *= scale; v.z *= scale; v.w *= scale;
    *(float4*)&p[tid * 4] = v;
}

// ---------------------------------------------------------------------------
// K5a: Cell_B convs + bias + squash(last=128) -> xbS[n][j=8][s=8][128]
// grid (s=8, n=64), 256 thr
__global__ __launch_bounds__(256) void k_cellB_conv(
    const float* __restrict__ x, const float* __restrict__ wB, const float* __restrict__ bB,
    const float* __restrict__ wk, const float* __restrict__ bk, float* __restrict__ xbS)
{
    const int s = blockIdx.x;
    const int n = blockIdx.y;
    __shared__ float wBl[64 * 64];    // 16 KB
    __shared__ float wkl[8 * 320];    // 10 KB
    __shared__ float xb1[64][132];    // 33.8 KB  (2-elem zero halo each side)
    __shared__ float redq[8][33];
    const int tid = threadIdx.x;
    for (int i = tid; i < 4096; i += 256) wBl[i] = wB[i];
    for (int i = tid; i < 2560; i += 256) wkl[i] = wk[i];
    for (int i = tid; i < 64; i += 256) {
        xb1[i][0] = xb1[i][1] = xb1[i][130] = xb1[i][131] = 0.f;
    }
    __syncthreads();

    // step 1: xb1[ch][t] = bB[ch] + sum_k wB[ch][k] * x[n][k][s*128+t]
    {
        const int t0  = (tid & 31) * 4;   // 0..124
        const int chg = tid >> 5;         // 0..7  -> ch = chg*8 + cc
        float acc[8][4] = {};
        const float* xbase = x + (size_t)n * TC_K * TC_L + s * TC_LN + t0;
        for (int k = 0; k < 64; ++k) {
            float4 xv = *(const float4*)&xbase[(size_t)k * TC_L];
            float v0 = xv.x, v1 = xv.y, v2 = xv.z, v3 = xv.w;
#pragma unroll
            for (int cc = 0; cc < 8; ++cc) {
                float w = wBl[(chg * 8 + cc) * 64 + k];
                acc[cc][0] = fmaf(w, v0, acc[cc][0]);
                acc[cc][1] = fmaf(w, v1, acc[cc][1]);
                acc[cc][2] = fmaf(w, v2, acc[cc][2]);
                acc[cc][3] = fmaf(w, v3, acc[cc][3]);
            }
        }
#pragma unroll
        for (int cc = 0; cc < 8; ++cc) {
            int ch = chg * 8 + cc;
            float b = bB[ch];
            xb1[ch][2 + t0 + 0] = acc[cc][0] + b;
            xb1[ch][2 + t0 + 1] = acc[cc][1] + b;
            xb1[ch][2 + t0 + 2] = acc[cc][2] + b;
            xb1[ch][2 + t0 + 3] = acc[cc][3] + b;
        }
    }
    __syncthreads();

    // step 2: xbB[j][t] = bk[j] + sum_{ch,dw} wk[j,ch,dw]*xb1[ch][t-2+dw]; squash over t
    {
        const int t0 = (tid & 31) * 4;
        const int j  = tid >> 5;          // 0..7
        float acc[4] = {};
        for (int ch = 0; ch < 64; ++ch) {
            float4 va = *(const float4*)&xb1[ch][t0];
            float4 vb = *(const float4*)&xb1[ch][t0 + 4];
            float v[8] = {va.x, va.y, va.z, va.w, vb.x, vb.y, vb.z, vb.w};
            const float* wp = &wkl[j * 320 + ch * 5];
#pragma unroll
            for (int dw = 0; dw < 5; ++dw) {
                float w = wp[dw];
#pragma unroll
                for (int q = 0; q < 4; ++q) acc[q] = fmaf(w, v[q + dw], acc[q]);
            }
        }
        float b = bk[j];
#pragma unroll
        for (int q = 0; q < 4; ++q) acc[q] += b;
        float part = acc[0]*acc[0] + acc[1]*acc[1] + acc[2]*acc[2] + acc[3]*acc[3];
        redq[j][tid & 31] = part;
        __syncthreads();
        for (int st = 16; st > 0; st >>= 1) {
            if ((tid & 31) < st) redq[j][tid & 31] += redq[j][(tid & 31) + st];
            __syncthreads();
        }
        float sq = redq[j][0];
        float scale = sq / ((1.f + sq) * (sq + 1e-8f));
        float* outp = xbS + (((size_t)n * 8 + j) * 8 + s) * TC_LN + t0;
        *(float4*)outp = make_float4(acc[0]*scale, acc[1]*scale, acc[2]*scale, acc[3]*scale);
    }
}

// ---------------------------------------------------------------------------
// K5b: routing over s for Cell_B -> xB[n][j][t]
// grid (j=8, n=64), 128 thr
__global__ __launch_bounds__(128) void k_routeB(
    const float* __restrict__ xbS, float* __restrict__ xB)
{
    const int j = blockIdx.x, n = blockIdx.y;
    const int t = threadIdx.x;
    float xv[8];
    const float* base = xbS + ((size_t)n * 8 + j) * 8 * TC_LN;
#pragma unroll
    for (int s = 0; s < 8; ++s) xv[s] = base[s * TC_LN + t];

    __shared__ float red[128];
    __shared__ float redp[8][129];

    // iter 1 (c uniform 1/8)
    float sj = 0.f;
#pragma unroll
    for (int s = 0; s < 8; ++s) sj += xv[s];
    sj *= 0.125f;
    red[t] = sj * sj;
    __syncthreads();
    for (int st = 64; st > 0; st >>= 1) { if (t < st) red[t] += red[t + st]; __syncthreads(); }
    float sq = red[0];
    float vfac = sq / ((1.f + sq) * (sq + 1e-8f));
    float vj = vfac * sj;
#pragma unroll
    for (int s = 0; s < 8; ++s) redp[s][t] = xv[s] * vj;
    __syncthreads();
    for (int st = 64; st > 0; st >>= 1) {
        if (t < st) {
#pragma unroll
            for (int s = 0; s < 8; ++s) redp[s][t] += redp[s][t + st];
        }
        __syncthreads();
    }
    float bv[8], bmax = -1e30f;
#pragma unroll
    for (int s = 0; s < 8; ++s) { bv[s] = redp[s][0]; bmax = fmaxf(bmax, bv[s]); }
    float esum = 0.f;
#pragma unroll
    for (int s = 0; s < 8; ++s) { bv[s] = __expf(bv[s] - bmax); esum += bv[s]; }
    float cinv = 1.f / esum;
    // iter 2
    float sj2 = 0.f;
#pragma unroll
    for (int s = 0; s < 8; ++s) sj2 += bv[s] * xv[s];
    sj2 *= cinv;
    __syncthreads();
    red[t] = sj2 * sj2;
    __syncthreads();
    for (int st = 64; st > 0; st >>= 1) { if (t < st) red[t] += red[t + st]; __syncthreads(); }
    float sq2 = red[0];
    float vfac2 = sq2 / ((1.f + sq2) * (sq2 + 1e-8f));
    xB[((size_t)n * 8 + j) * TC_LN + t] = vfac2 * sj2;
}

// ---------------------------------------------------------------------------
// K4: Cell_A conv2d (8x3, stride 8 over caps) + bias + routing over p -> vjA[n][o][l]
// grid (o=64, n=64), 256 thr; conv outputs kept in registers.
// R1: #pragma unroll 1 on the p loop (limits in-flight loads -> VGPR),
//     __launch_bounds__(256,4) forces <=128 VGPR -> 4 waves/SIMD.
__global__ __launch_bounds__(256, 4) void k_cellA(
    const float* __restrict__ xs, const float* __restrict__ wA, const float* __restrict__ bA,
    float* __restrict__ vjA)
{
    const int o = blockIdx.x;
    const int n = blockIdx.y;
    const int tid = threadIdx.x;
    const int l0 = tid * 4;

    float w[24];
#pragma unroll
    for (int i = 0; i < 24; ++i) w[i] = wA[o * 24 + i];
    const float bias = bA[o];

    const float* xsn = xs + (size_t)n * TC_K * TC_L;
    float xrv[8][4];
#pragma unroll 1
    for (int p = 0; p < 8; ++p) {
        float a0 = bias, a1 = bias, a2 = bias, a3 = bias;
#pragma unroll
        for (int dh = 0; dh < 8; ++dh) {
            const float* row = xsn + (p * 8 + dh) * TC_L;
            float4 vm = *(const float4*)&row[l0];
            float vl = (l0 > 0) ? row[l0 - 1] : 0.f;
            float vr = (l0 + 4 < TC_L) ? row[l0 + 4] : 0.f;
            float w0 = w[dh * 3 + 0], w1 = w[dh * 3 + 1], w2 = w[dh * 3 + 2];
            a0 = fmaf(w0, vl,   a0); a0 = fmaf(w1, vm.x, a0); a0 = fmaf(w2, vm.y, a0);
            a1 = fmaf(w0, vm.x, a1); a1 = fmaf(w1, vm.y, a1); a1 = fmaf(w2, vm.z, a1);
            a2 = fmaf(w0, vm.y, a2); a2 = fmaf(w1, vm.z, a2); a2 = fmaf(w2, vm.w, a2);
            a3 = fmaf(w0, vm.z, a3); a3 = fmaf(w1, vm.w, a3); a3 = fmaf(w2, vr,   a3);
        }
        xrv[p][0] = a0; xrv[p][1] = a1; xrv[p][2] = a2; xrv[p][3] = a3;
    }

    __shared__ float red[256];
    __shared__ float redp[8][257];

    // routing iter 1
    float sjv[4];
    float part = 0.f;
#pragma unroll
    for (int jj = 0; jj < 4; ++jj) {
        float sv = 0.f;
#pragma unroll
        for (int p = 0; p < 8; ++p) sv += xrv[p][jj];
        sv *= 0.125f;
        sjv[jj] = sv;
        part += sv * sv;
    }
    red[tid] = part;
    __syncthreads();
    for (int st = 128; st > 0; st >>= 1) { if (tid < st) red[tid] += red[tid + st]; __syncthreads(); }
    float sq = red[0];
    float vfac = sq / ((1.f + sq) * (sq + 1e-8f));
    float bp[8] = {};
#pragma unroll
    for (int jj = 0; jj < 4; ++jj) {
        float vj = vfac * sjv[jj];
#pragma unroll
        for (int p = 0; p < 8; ++p) bp[p] += xrv[p][jj] * vj;
    }
#pragma unroll
    for (int p = 0; p < 8; ++p) redp[p][tid] = bp[p];
    __syncthreads();
    for (int st = 128; st > 0; st >>= 1) {
        if (tid < st) {
#pragma unroll
            for (int p = 0; p < 8; ++p) redp[p][tid] += redp[p][tid + st];
        }
        __syncthreads();
    }
    float bv[8], bmax = -1e30f;
#pragma unroll
    for (int p = 0; p < 8; ++p) { bv[p] = redp[p][0]; bmax = fmaxf(bmax, bv[p]); }
    float esum = 0.f;
#pragma unroll
    for (int p = 0; p < 8; ++p) { bv[p] = __expf(bv[p] - bmax); esum += bv[p]; }
    float cinv = 1.f / esum;
    // iter 2
    float sj2[4]; float part2 = 0.f;
#pragma unroll
    for (int jj = 0; jj < 4; ++jj) {
        float sv = 0.f;
#pragma unroll
        for (int p = 0; p < 8; ++p) sv += bv[p] * xrv[p][jj];
        sv *= cinv;
        sj2[jj] = sv;
        part2 += sv * sv;
    }
    __syncthreads();
    red[tid] = part2;
    __syncthreads();
    for (int st = 128; st > 0; st >>= 1) { if (tid < st) red[tid] += red[tid + st]; __syncthreads(); }
    float sq2 = red[0];
    float vfac2 = sq2 / ((1.f + sq2) * (sq2 + 1e-8f));
    float* outp = vjA + ((size_t)n * 64 + o) * TC_L + l0;
    *(float4*)outp = make_float4(vfac2*sj2[0], vfac2*sj2[1], vfac2*sj2[2], vfac2*sj2[3]);
}

// ---------------------------------------------------------------------------
// K6: DigitCaps u[c,o] = sum_d xcat[c,d]*W[k,d,o] + routing over c -> out[n,k,o]
// grid (kcls=10, n=64), 256 thr (= 16 o x 16 d-lanes)
__global__ __launch_bounds__(256) void k_digit(
    const float* __restrict__ vjA, const float* __restrict__ xB,
    const float* __restrict__ W, const float* __restrict__ alphap,
    const float* __restrict__ betap, float* __restrict__ out)
{
    const int kc = blockIdx.x;
    const int n = blockIdx.y;
    const int tid = threadIdx.x;
    const int o  = tid & 15;
    const int dl = tid >> 4;     // 0..15
    const float alpha = alphap[0], beta = betap[0];

    __shared__ float xT[512][8];     // 16 KB, [dd][c]
    float acc[8] = {};

    const float* vjAn = vjA + (size_t)n * 65536;
    const float* xBn  = xB  + (size_t)n * 1024;
    const float* Wk   = W   + (size_t)kc * (TC_DCAT * 16);

    for (int d0 = 0; d0 < TC_DCAT; d0 += 512) {
        __syncthreads();
        for (int i = tid; i < 512 * 8; i += 256) {
            int c = i >> 9;
            int dd = i & 511;
            int d = d0 + dd;
            float v = 0.f;
            if (d < 8192) v = alpha * vjAn[c * 8192 + d];
            else if (d < TC_DCAT) v = beta * xBn[c * 128 + (d - 8192)];
            xT[dd][c] = v;
        }
        __syncthreads();
#pragma unroll 4
        for (int i = 0; i < 32; ++i) {
            int d = dl + i * 16;
            int gd = d0 + d;
            int cl = gd < TC_DCAT ? gd : (TC_DCAT - 1);
            float wv = Wk[cl * 16 + o];
            float4 xa = *(const float4*)&xT[d][0];
            float4 xb = *(const float4*)&xT[d][4];
            acc[0] = fmaf(wv, xa.x, acc[0]);
            acc[1] = fmaf(wv, xa.y, acc[1]);
            acc[2] = fmaf(wv, xa.z, acc[2]);
            acc[3] = fmaf(wv, xa.w, acc[3]);
            acc[4] = fmaf(wv, xb.x, acc[4]);
            acc[5] = fmaf(wv, xb.y, acc[5]);
            acc[6] = fmaf(wv, xb.z, acc[6]);
            acc[7] = fmaf(wv, xb.w, acc[7]);
        }
    }

    __shared__ float redu[16][8][17];
#pragma unroll
    for (int c = 0; c < 8; ++c) redu[dl][c][o] = acc[c];
    __syncthreads();
    __shared__ float ul[8][16];
    if (tid < 128) {
        int c = tid >> 4, oo = tid & 15;
        float sv = 0.f;
#pragma unroll
        for (int q = 0; q < 16; ++q) sv += redu[q][c][oo];
        ul[c][oo] = sv;
    }
    __syncthreads();

    __shared__ float sjo[16];
    __shared__ float bc[8];
    __shared__ float fac[1];
    // routing iter 1
    if (tid < 16) {
        float sv = 0.f;
#pragma unroll
        for (int c = 0; c < 8; ++c) sv += ul[c][tid];
        sjo[tid] = sv * 0.125f;
    }
    __syncthreads();
    if (tid == 0) {
        float sq = 0.f;
#pragma unroll
        for (int oo = 0; oo < 16; ++oo) sq += sjo[oo] * sjo[oo];
        fac[0] = sq / ((1.f + sq) * (sq + 1e-8f));
    }
    __syncthreads();
    if (tid < 8) {
        float vf = fac[0];
        float sv = 0.f;
#pragma unroll
        for (int oo = 0; oo < 16; ++oo) sv += ul[tid][oo] * (vf * sjo[oo]);
        bc[tid] = sv;
    }
    __syncthreads();
    // iter 2
    if (tid < 16) {
        float bmax = -1e30f;
#pragma unroll
        for (int c = 0; c < 8; ++c) bmax = fmaxf(bmax, bc[c]);
        float e[8]; float es = 0.f;
#pragma unroll
        for (int c = 0; c < 8; ++c) { e[c] = __expf(bc[c] - bmax); es += e[c]; }
        float inv = 1.f / es;
        float sv = 0.f;
#pragma unroll
        for (int c = 0; c < 8; ++c) sv += e[c] * inv * ul[c][tid];
        sjo[tid] = sv;
    }
    __syncthreads();
    if (tid == 0) {
        float sq = 0.f;
#pragma unroll
        for (int oo = 0; oo < 16; ++oo) sq += sjo[oo] * sjo[oo];
        fac[0] = sq / ((1.f + sq) * (sq + 1e-8f));
    }
    __syncthreads();
    if (tid < 16) {
        out[((size_t)n * TC_NCLS + kc) * 16 + tid] = fac[0] * sjo[tid];
    }
}

// ---------------------------------------------------------------------------
extern "C" void kernel_launch(void* const* d_in, const int* in_sizes, int n_in,
                              void* d_out, int out_size, void* d_ws, size_t ws_size,
                              hipStream_t stream) {
    const float* X   = (const float*)d_in[0];
    const float* w1  = (const float*)d_in[1];
    const float* w2  = (const float*)d_in[2];
    const float* wA  = (const float*)d_in[3];
    const float* bA  = (const float*)d_in[4];
    const float* wB  = (const float*)d_in[5];
    const float* bB  = (const float*)d_in[6];
    const float* wk  = (const float*)d_in[7];
    const float* bk  = (const float*)d_in[8];
    const float* Wd  = (const float*)d_in[9];
    const float* alphap = (const float*)d_in[10];
    const float* betap  = (const float*)d_in[11];
    float* out = (float*)d_out;

    float* ws  = (float*)d_ws;
    float* x   = ws;                 // [64][64][1024] conv1 out; reused as vjA after Cell_B conv
    float* xs  = ws + 4194304;       // [64][64][1024] psi_m out, squashed in place
    float* xbS = ws + 8388608;       // [64][8][8][128]
    float* xB  = ws + 8912896;       // [64][8][128]
    float* vjA = x;                  // alias (x dead after k_cellB_conv)

    k_conv1<<<dim3(64, 64), 256, 0, stream>>>(X, w1, x);
    k_psim<<<dim3(8, 64), 256, 0, stream>>>(x, w2, xs);
    k_squash_rows<<<dim3(4096), 256, 0, stream>>>(xs);
    k_cellB_conv<<<dim3(8, 64), 256, 0, stream>>>(x, wB, bB, wk, bk, xbS);
    k_routeB<<<dim3(8, 64), 128, 0, stream>>>(xbS, xB);
    k_cellA<<<dim3(64, 64), 256, 0, stream>>>(xs, wA, bA, vjA);
    k_digit<<<dim3(10, 64), 256, 0, stream>>>(vjA, xB, Wd, alphap, betap, out);
}

// Round 4
// 471.067 us; speedup vs baseline: 1.2529x; 1.0694x over previous
//
#include <hip/hip_runtime.h>

#define TC_L    1024
#define TC_K    64
#define TC_LN   128
#define TC_NCLS 10
#define TC_DCAT 8320

// ---------------------------------------------------------------------------
// K1: conv1  x[n,k,l] = sum_t w1[k,t] * X[n, l-4+t]   (pad 4)
// grid (k=64, n=64), 256 thr
__global__ __launch_bounds__(256) void k_conv1(
    const float* __restrict__ X, const float* __restrict__ w1, float* __restrict__ x)
{
    const int k = blockIdx.x, n = blockIdx.y;
    float w[9];
#pragma unroll
    for (int t = 0; t < 9; ++t) w[t] = w1[k * 9 + t];
    const float* xin = X + n * TC_L;
    float* out = x + (n * TC_K + k) * TC_L;
    for (int l = threadIdx.x; l < TC_L; l += 256) {
        float acc = 0.f;
#pragma unroll
        for (int t = 0; t < 9; ++t) {
            int idx = l - 4 + t;
            float v = (idx >= 0 && idx < TC_L) ? xin[idx] : 0.f;
            acc = fmaf(w[t], v, acc);
        }
        out[l] = acc;
    }
}

// ---------------------------------------------------------------------------
// K2: psi_m conv  xs[n,oc,l] = sum_{ic,t} w2[oc,ic,t] * x[n,ic,l-2+t]  (pad 2)
// grid (ocb=8, n=64), 256 thr, 8 oc per block, L chunked by 256
__global__ __launch_bounds__(256) void k_psim(
    const float* __restrict__ x, const float* __restrict__ w2, float* __restrict__ xs)
{
    const int ocb = blockIdx.x;
    const int n = blockIdx.y;
    __shared__ float wl[8 * 320];     // 10 KB
    __shared__ float xl[64][260];     // 66.6 KB
    const int tid = threadIdx.x;
    for (int i = tid; i < 8 * 320; i += 256) wl[i] = w2[ocb * 8 * 320 + i];

    const int lgrp = tid & 63;        // 0..63 -> l0 = lgrp*4
    const int ocg  = tid >> 6;        // 0..3  -> oc pair base = ocg*2
    const int l0 = lgrp * 4;
    const int oc0 = ocg * 2;

    for (int lc = 0; lc < TC_L; lc += 256) {
        __syncthreads();
        for (int i = tid; i < 64 * 260; i += 256) {
            int ic = i / 260, d = i - ic * 260;
            int gl = lc - 2 + d;
            xl[ic][d] = (gl >= 0 && gl < TC_L) ? x[(n * TC_K + ic) * TC_L + gl] : 0.f;
        }
        __syncthreads();
        float acc[2][4] = {};
        for (int ic = 0; ic < 64; ++ic) {
            float4 va = *(const float4*)&xl[ic][l0];
            float4 vb = *(const float4*)&xl[ic][l0 + 4];
            float v[8] = {va.x, va.y, va.z, va.w, vb.x, vb.y, vb.z, vb.w};
            const float* wp0 = &wl[(oc0 + 0) * 320 + ic * 5];
            const float* wp1 = &wl[(oc0 + 1) * 320 + ic * 5];
#pragma unroll
            for (int t = 0; t < 5; ++t) {
                float w0 = wp0[t], w1 = wp1[t];
#pragma unroll
                for (int j = 0; j < 4; ++j) {
                    acc[0][j] = fmaf(w0, v[j + t], acc[0][j]);
                    acc[1][j] = fmaf(w1, v[j + t], acc[1][j]);
                }
            }
        }
#pragma unroll
        for (int q = 0; q < 2; ++q) {
            int oc = ocb * 8 + oc0 + q;
            *(float4*)&xs[(n * TC_K + oc) * TC_L + lc + l0] =
                make_float4(acc[q][0], acc[q][1], acc[q][2], acc[q][3]);
        }
    }
}

// ---------------------------------------------------------------------------
// K3: squash each row of 1024 in place
__global__ __launch_bounds__(256) void k_squash_rows(float* __restrict__ xs)
{
    const int row = blockIdx.x;
    float* p = xs + (size_t)row * TC_L;
    const int tid = threadIdx.x;
    float4 v = *(const float4*)&p[tid * 4];
    float part = v.x * v.x + v.y * v.y + v.z * v.z + v.w * v.w;
    __shared__ float red[256];
    red[tid] = part;
    __syncthreads();
    for (int s = 128; s > 0; s >>= 1) {
        if (tid < s) red[tid] += red[tid + s];
        __syncthreads();
    }
    float sq = red[0];
    float scale = sq / ((1.f + sq) * (sq + 1e-8f));
    v.x *= scale; v.y *= scale; v.z *= scale; v.w *= scale;
    *(float4*)&p[tid * 4] = v;
}

// ---------------------------------------------------------------------------
// K5a: Cell_B convs + bias + squash(last=128) -> xbS[n][j=8][s=8][128]
// grid (s=8, n=64), 256 thr
__global__ __launch_bounds__(256) void k_cellB_conv(
    const float* __restrict__ x, const float* __restrict__ wB, const float* __restrict__ bB,
    const float* __restrict__ wk, const float* __restrict__ bk, float* __restrict__ xbS)
{
    const int s = blockIdx.x;
    const int n = blockIdx.y;
    __shared__ float wBl[64 * 64];    // 16 KB
    __shared__ float wkl[8 * 320];    // 10 KB
    __shared__ float xb1[64][132];    // 33.8 KB  (2-elem zero halo each side)
    __shared__ float redq[8][33];
    const int tid = threadIdx.x;
    for (int i = tid; i < 4096; i += 256) wBl[i] = wB[i];
    for (int i = tid; i < 2560; i += 256) wkl[i] = wk[i];
    for (int i = tid; i < 64; i += 256) {
        xb1[i][0] = xb1[i][1] = xb1[i][130] = xb1[i][131] = 0.f;
    }
    __syncthreads();

    {
        const int t0  = (tid & 31) * 4;   // 0..124
        const int chg = tid >> 5;         // 0..7
        float acc[8][4] = {};
        const float* xbase = x + (size_t)n * TC_K * TC_L + s * TC_LN + t0;
        for (int k = 0; k < 64; ++k) {
            float4 xv = *(const float4*)&xbase[(size_t)k * TC_L];
            float v0 = xv.x, v1 = xv.y, v2 = xv.z, v3 = xv.w;
#pragma unroll
            for (int cc = 0; cc < 8; ++cc) {
                float w = wBl[(chg * 8 + cc) * 64 + k];
                acc[cc][0] = fmaf(w, v0, acc[cc][0]);
                acc[cc][1] = fmaf(w, v1, acc[cc][1]);
                acc[cc][2] = fmaf(w, v2, acc[cc][2]);
                acc[cc][3] = fmaf(w, v3, acc[cc][3]);
            }
        }
#pragma unroll
        for (int cc = 0; cc < 8; ++cc) {
            int ch = chg * 8 + cc;
            float b = bB[ch];
            xb1[ch][2 + t0 + 0] = acc[cc][0] + b;
            xb1[ch][2 + t0 + 1] = acc[cc][1] + b;
            xb1[ch][2 + t0 + 2] = acc[cc][2] + b;
            xb1[ch][2 + t0 + 3] = acc[cc][3] + b;
        }
    }
    __syncthreads();

    {
        const int t0 = (tid & 31) * 4;
        const int j  = tid >> 5;          // 0..7
        float acc[4] = {};
        for (int ch = 0; ch < 64; ++ch) {
            float4 va = *(const float4*)&xb1[ch][t0];
            float4 vb = *(const float4*)&xb1[ch][t0 + 4];
            float v[8] = {va.x, va.y, va.z, va.w, vb.x, vb.y, vb.z, vb.w};
            const float* wp = &wkl[j * 320 + ch * 5];
#pragma unroll
            for (int dw = 0; dw < 5; ++dw) {
                float w = wp[dw];
#pragma unroll
                for (int q = 0; q < 4; ++q) acc[q] = fmaf(w, v[q + dw], acc[q]);
            }
        }
        float b = bk[j];
#pragma unroll
        for (int q = 0; q < 4; ++q) acc[q] += b;
        float part = acc[0]*acc[0] + acc[1]*acc[1] + acc[2]*acc[2] + acc[3]*acc[3];
        redq[j][tid & 31] = part;
        __syncthreads();
        for (int st = 16; st > 0; st >>= 1) {
            if ((tid & 31) < st) redq[j][tid & 31] += redq[j][(tid & 31) + st];
            __syncthreads();
        }
        float sq = redq[j][0];
        float scale = sq / ((1.f + sq) * (sq + 1e-8f));
        float* outp = xbS + (((size_t)n * 8 + j) * 8 + s) * TC_LN + t0;
        *(float4*)outp = make_float4(acc[0]*scale, acc[1]*scale, acc[2]*scale, acc[3]*scale);
    }
}

// ---------------------------------------------------------------------------
// K5b: routing over s for Cell_B -> xB[n][j][t]
__global__ __launch_bounds__(128) void k_routeB(
    const float* __restrict__ xbS, float* __restrict__ xB)
{
    const int j = blockIdx.x, n = blockIdx.y;
    const int t = threadIdx.x;
    float xv[8];
    const float* base = xbS + ((size_t)n * 8 + j) * 8 * TC_LN;
#pragma unroll
    for (int s = 0; s < 8; ++s) xv[s] = base[s * TC_LN + t];

    __shared__ float red[128];
    __shared__ float redp[8][129];

    float sj = 0.f;
#pragma unroll
    for (int s = 0; s < 8; ++s) sj += xv[s];
    sj *= 0.125f;
    red[t] = sj * sj;
    __syncthreads();
    for (int st = 64; st > 0; st >>= 1) { if (t < st) red[t] += red[t + st]; __syncthreads(); }
    float sq = red[0];
    float vfac = sq / ((1.f + sq) * (sq + 1e-8f));
    float vj = vfac * sj;
#pragma unroll
    for (int s = 0; s < 8; ++s) redp[s][t] = xv[s] * vj;
    __syncthreads();
    for (int st = 64; st > 0; st >>= 1) {
        if (t < st) {
#pragma unroll
            for (int s = 0; s < 8; ++s) redp[s][t] += redp[s][t + st];
        }
        __syncthreads();
    }
    float bv[8], bmax = -1e30f;
#pragma unroll
    for (int s = 0; s < 8; ++s) { bv[s] = redp[s][0]; bmax = fmaxf(bmax, bv[s]); }
    float esum = 0.f;
#pragma unroll
    for (int s = 0; s < 8; ++s) { bv[s] = __expf(bv[s] - bmax); esum += bv[s]; }
    float cinv = 1.f / esum;
    float sj2 = 0.f;
#pragma unroll
    for (int s = 0; s < 8; ++s) sj2 += bv[s] * xv[s];
    sj2 *= cinv;
    __syncthreads();
    red[t] = sj2 * sj2;
    __syncthreads();
    for (int st = 64; st > 0; st >>= 1) { if (t < st) red[t] += red[t + st]; __syncthreads(); }
    float sq2 = red[0];
    float vfac2 = sq2 / ((1.f + sq2) * (sq2 + 1e-8f));
    xB[((size_t)n * 8 + j) * TC_LN + t] = vfac2 * sj2;
}

// ---------------------------------------------------------------------------
// K4a: Cell_A conv for all 64 o, one l-chunk of 64, one n.
// grid (16 chunks, 32 n), 256 thr = 16 l-strips x 16 o-groups(4 o each)
// Stages the 64 input rows ONCE per block -> kills the 64x re-read.
__global__ __launch_bounds__(256) void k_cellA_conv(
    const float* __restrict__ xs, const float* __restrict__ wA, const float* __restrict__ bA,
    float* __restrict__ xa, int n0)
{
    const int lc = blockIdx.x * 64;
    const int nrel = blockIdx.y;
    const int n = n0 + nrel;
    const int tid = threadIdx.x;
    __shared__ float xl[64][68];      // cols c=0..65 <-> global l = lc + c - 1
    __shared__ float wl[64 * 24];
    __shared__ float bl[64];
    for (int i = tid; i < 64 * 24; i += 256) wl[i] = wA[i];
    if (tid < 64) bl[tid] = bA[tid];
    const float* xsn = xs + (size_t)n * (TC_K * TC_L);
    for (int i = tid; i < 64 * 66; i += 256) {
        int k = i / 66, c = i - k * 66;
        int gl = lc + c - 1;
        xl[k][c] = (gl >= 0 && gl < TC_L) ? xsn[k * TC_L + gl] : 0.f;
    }
    __syncthreads();

    const int strip = tid & 15;       // l0 = strip*4
    const int g = tid >> 4;           // o = g*4 + oi
    const int l0 = strip * 4;
    float* xab = xa + (size_t)nrel * 64 * 8192;   // [o][p][1024]

#pragma unroll 1
    for (int oi = 0; oi < 4; ++oi) {
        const int o = g * 4 + oi;
        float w[24];
#pragma unroll
        for (int i = 0; i < 24; ++i) w[i] = wl[o * 24 + i];
        const float bias = bl[o];
#pragma unroll
        for (int p = 0; p < 8; ++p) {
            float a0 = bias, a1 = bias, a2 = bias, a3 = bias;
#pragma unroll
            for (int dh = 0; dh < 8; ++dh) {
                const float* row = &xl[p * 8 + dh][l0];
                float4 va = *(const float4*)row;          // c = l0..l0+3
                float2 vb = *(const float2*)(row + 4);    // c = l0+4, l0+5
                float w0 = w[dh * 3], w1 = w[dh * 3 + 1], w2 = w[dh * 3 + 2];
                a0 = fmaf(w0, va.x, a0); a0 = fmaf(w1, va.y, a0); a0 = fmaf(w2, va.z, a0);
                a1 = fmaf(w0, va.y, a1); a1 = fmaf(w1, va.z, a1); a1 = fmaf(w2, va.w, a1);
                a2 = fmaf(w0, va.z, a2); a2 = fmaf(w1, va.w, a2); a2 = fmaf(w2, vb.x, a2);
                a3 = fmaf(w0, va.w, a3); a3 = fmaf(w1, vb.x, a3); a3 = fmaf(w2, vb.y, a3);
            }
            *(float4*)&xab[(size_t)o * 8192 + p * TC_L + lc + l0] = make_float4(a0, a1, a2, a3);
        }
    }
}

// ---------------------------------------------------------------------------
// K4b: routing over p from xa (contiguous 32KB per (n,o)), coalesced loads.
// grid (o=64, 32 n), 256 thr
__global__ __launch_bounds__(256) void k_cellA_route(
    const float* __restrict__ xa, float* __restrict__ vjA, int n0)
{
    const int o = blockIdx.x;
    const int nrel = blockIdx.y;
    const int n = n0 + nrel;
    const int tid = threadIdx.x;
    const int l0 = tid * 4;
    const float* base = xa + ((size_t)nrel * 64 + o) * 8192;

    float xrv[8][4];
#pragma unroll
    for (int p = 0; p < 8; ++p) {
        float4 v = *(const float4*)&base[p * TC_L + l0];
        xrv[p][0] = v.x; xrv[p][1] = v.y; xrv[p][2] = v.z; xrv[p][3] = v.w;
    }

    __shared__ float red[256];
    __shared__ float redp[8][257];

    // routing iter 1
    float sjv[4];
    float part = 0.f;
#pragma unroll
    for (int jj = 0; jj < 4; ++jj) {
        float sv = 0.f;
#pragma unroll
        for (int p = 0; p < 8; ++p) sv += xrv[p][jj];
        sv *= 0.125f;
        sjv[jj] = sv;
        part += sv * sv;
    }
    red[tid] = part;
    __syncthreads();
    for (int st = 128; st > 0; st >>= 1) { if (tid < st) red[tid] += red[tid + st]; __syncthreads(); }
    float sq = red[0];
    float vfac = sq / ((1.f + sq) * (sq + 1e-8f));
    float bp[8] = {};
#pragma unroll
    for (int jj = 0; jj < 4; ++jj) {
        float vj = vfac * sjv[jj];
#pragma unroll
        for (int p = 0; p < 8; ++p) bp[p] += xrv[p][jj] * vj;
    }
#pragma unroll
    for (int p = 0; p < 8; ++p) redp[p][tid] = bp[p];
    __syncthreads();
    for (int st = 128; st > 0; st >>= 1) {
        if (tid < st) {
#pragma unroll
            for (int p = 0; p < 8; ++p) redp[p][tid] += redp[p][tid + st];
        }
        __syncthreads();
    }
    float bv[8], bmax = -1e30f;
#pragma unroll
    for (int p = 0; p < 8; ++p) { bv[p] = redp[p][0]; bmax = fmaxf(bmax, bv[p]); }
    float esum = 0.f;
#pragma unroll
    for (int p = 0; p < 8; ++p) { bv[p] = __expf(bv[p] - bmax); esum += bv[p]; }
    float cinv = 1.f / esum;
    // iter 2
    float sj2[4]; float part2 = 0.f;
#pragma unroll
    for (int jj = 0; jj < 4; ++jj) {
        float sv = 0.f;
#pragma unroll
        for (int p = 0; p < 8; ++p) sv += bv[p] * xrv[p][jj];
        sv *= cinv;
        sj2[jj] = sv;
        part2 += sv * sv;
    }
    __syncthreads();
    red[tid] = part2;
    __syncthreads();
    for (int st = 128; st > 0; st >>= 1) { if (tid < st) red[tid] += red[tid + st]; __syncthreads(); }
    float sq2 = red[0];
    float vfac2 = sq2 / ((1.f + sq2) * (sq2 + 1e-8f));
    float* outp = vjA + ((size_t)n * 64 + o) * TC_L + l0;
    *(float4*)outp = make_float4(vfac2*sj2[0], vfac2*sj2[1], vfac2*sj2[2], vfac2*sj2[3]);
}

// ---------------------------------------------------------------------------
// K4 (fallback, R1 version): fused Cell_A — used only if ws too small for xa.
__global__ __launch_bounds__(256, 4) void k_cellA(
    const float* __restrict__ xs, const float* __restrict__ wA, const float* __restrict__ bA,
    float* __restrict__ vjA)
{
    const int o = blockIdx.x;
    const int n = blockIdx.y;
    const int tid = threadIdx.x;
    const int l0 = tid * 4;

    float w[24];
#pragma unroll
    for (int i = 0; i < 24; ++i) w[i] = wA[o * 24 + i];
    const float bias = bA[o];

    const float* xsn = xs + (size_t)n * TC_K * TC_L;
    float xrv[8][4];
#pragma unroll 1
    for (int p = 0; p < 8; ++p) {
        float a0 = bias, a1 = bias, a2 = bias, a3 = bias;
#pragma unroll
        for (int dh = 0; dh < 8; ++dh) {
            const float* row = xsn + (p * 8 + dh) * TC_L;
            float4 vm = *(const float4*)&row[l0];
            float vl = (l0 > 0) ? row[l0 - 1] : 0.f;
            float vr = (l0 + 4 < TC_L) ? row[l0 + 4] : 0.f;
            float w0 = w[dh * 3 + 0], w1 = w[dh * 3 + 1], w2 = w[dh * 3 + 2];
            a0 = fmaf(w0, vl,   a0); a0 = fmaf(w1, vm.x, a0); a0 = fmaf(w2, vm.y, a0);
            a1 = fmaf(w0, vm.x, a1); a1 = fmaf(w1, vm.y, a1); a1 = fmaf(w2, vm.z, a1);
            a2 = fmaf(w0, vm.y, a2); a2 = fmaf(w1, vm.z, a2); a2 = fmaf(w2, vm.w, a2);
            a3 = fmaf(w0, vm.z, a3); a3 = fmaf(w1, vm.w, a3); a3 = fmaf(w2, vr,   a3);
        }
        xrv[p][0] = a0; xrv[p][1] = a1; xrv[p][2] = a2; xrv[p][3] = a3;
    }

    __shared__ float red[256];
    __shared__ float redp[8][257];

    float sjv[4];
    float part = 0.f;
#pragma unroll
    for (int jj = 0; jj < 4; ++jj) {
        float sv = 0.f;
#pragma unroll
        for (int p = 0; p < 8; ++p) sv += xrv[p][jj];
        sv *= 0.125f;
        sjv[jj] = sv;
        part += sv * sv;
    }
    red[tid] = part;
    __syncthreads();
    for (int st = 128; st > 0; st >>= 1) { if (tid < st) red[tid] += red[tid + st]; __syncthreads(); }
    float sq = red[0];
    float vfac = sq / ((1.f + sq) * (sq + 1e-8f));
    float bp[8] = {};
#pragma unroll
    for (int jj = 0; jj < 4; ++jj) {
        float vj = vfac * sjv[jj];
#pragma unroll
        for (int p = 0; p < 8; ++p) bp[p] += xrv[p][jj] * vj;
    }
#pragma unroll
    for (int p = 0; p < 8; ++p) redp[p][tid] = bp[p];
    __syncthreads();
    for (int st = 128; st > 0; st >>= 1) {
        if (tid < st) {
#pragma unroll
            for (int p = 0; p < 8; ++p) redp[p][tid] += redp[p][tid + st];
        }
        __syncthreads();
    }
    float bv[8], bmax = -1e30f;
#pragma unroll
    for (int p = 0; p < 8; ++p) { bv[p] = redp[p][0]; bmax = fmaxf(bmax, bv[p]); }
    float esum = 0.f;
#pragma unroll
    for (int p = 0; p < 8; ++p) { bv[p] = __expf(bv[p] - bmax); esum += bv[p]; }
    float cinv = 1.f / esum;
    float sj2[4]; float part2 = 0.f;
#pragma unroll
    for (int jj = 0; jj < 4; ++jj) {
        float sv = 0.f;
#pragma unroll
        for (int p = 0; p < 8; ++p) sv += bv[p] * xrv[p][jj];
        sv *= cinv;
        sj2[jj] = sv;
        part2 += sv * sv;
    }
    __syncthreads();
    red[tid] = part2;
    __syncthreads();
    for (int st = 128; st > 0; st >>= 1) { if (tid < st) red[tid] += red[tid + st]; __syncthreads(); }
    float sq2 = red[0];
    float vfac2 = sq2 / ((1.f + sq2) * (sq2 + 1e-8f));
    float* outp = vjA + ((size_t)n * 64 + o) * TC_L + l0;
    *(float4*)outp = make_float4(vfac2*sj2[0], vfac2*sj2[1], vfac2*sj2[2], vfac2*sj2[3]);
}

// ---------------------------------------------------------------------------
// K6: DigitCaps u[c,o] = sum_d xcat[c,d]*W[k,d,o] + routing over c -> out[n,k,o]
// grid (kcls=10, n=64), 256 thr (= 16 o x 16 d-lanes)
__global__ __launch_bounds__(256) void k_digit(
    const float* __restrict__ vjA, const float* __restrict__ xB,
    const float* __restrict__ W, const float* __restrict__ alphap,
    const float* __restrict__ betap, float* __restrict__ out)
{
    const int kc = blockIdx.x;
    const int n = blockIdx.y;
    const int tid = threadIdx.x;
    const int o  = tid & 15;
    const int dl = tid >> 4;     // 0..15
    const float alpha = alphap[0], beta = betap[0];

    __shared__ float xT[512][8];     // 16 KB, [dd][c]
    float acc[8] = {};

    const float* vjAn = vjA + (size_t)n * 65536;
    const float* xBn  = xB  + (size_t)n * 1024;
    const float* Wk   = W   + (size_t)kc * (TC_DCAT * 16);

    for (int d0 = 0; d0 < TC_DCAT; d0 += 512) {
        __syncthreads();
        for (int i = tid; i < 512 * 8; i += 256) {
            int c = i >> 9;
            int dd = i & 511;
            int d = d0 + dd;
            float v = 0.f;
            if (d < 8192) v = alpha * vjAn[c * 8192 + d];
            else if (d < TC_DCAT) v = beta * xBn[c * 128 + (d - 8192)];
            xT[dd][c] = v;
        }
        __syncthreads();
#pragma unroll 4
        for (int i = 0; i < 32; ++i) {
            int d = dl + i * 16;
            int gd = d0 + d;
            int cl = gd < TC_DCAT ? gd : (TC_DCAT - 1);
            float wv = Wk[cl * 16 + o];
            float4 xa = *(const float4*)&xT[d][0];
            float4 xb = *(const float4*)&xT[d][4];
            acc[0] = fmaf(wv, xa.x, acc[0]);
            acc[1] = fmaf(wv, xa.y, acc[1]);
            acc[2] = fmaf(wv, xa.z, acc[2]);
            acc[3] = fmaf(wv, xa.w, acc[3]);
            acc[4] = fmaf(wv, xb.x, acc[4]);
            acc[5] = fmaf(wv, xb.y, acc[5]);
            acc[6] = fmaf(wv, xb.z, acc[6]);
            acc[7] = fmaf(wv, xb.w, acc[7]);
        }
    }

    __shared__ float redu[16][8][17];
#pragma unroll
    for (int c = 0; c < 8; ++c) redu[dl][c][o] = acc[c];
    __syncthreads();
    __shared__ float ul[8][16];
    if (tid < 128) {
        int c = tid >> 4, oo = tid & 15;
        float sv = 0.f;
#pragma unroll
        for (int q = 0; q < 16; ++q) sv += redu[q][c][oo];
        ul[c][oo] = sv;
    }
    __syncthreads();

    __shared__ float sjo[16];
    __shared__ float bc[8];
    __shared__ float fac[1];
    if (tid < 16) {
        float sv = 0.f;
#pragma unroll
        for (int c = 0; c < 8; ++c) sv += ul[c][tid];
        sjo[tid] = sv * 0.125f;
    }
    __syncthreads();
    if (tid == 0) {
        float sq = 0.f;
#pragma unroll
        for (int oo = 0; oo < 16; ++oo) sq += sjo[oo] * sjo[oo];
        fac[0] = sq / ((1.f + sq) * (sq + 1e-8f));
    }
    __syncthreads();
    if (tid < 8) {
        float vf = fac[0];
        float sv = 0.f;
#pragma unroll
        for (int oo = 0; oo < 16; ++oo) sv += ul[tid][oo] * (vf * sjo[oo]);
        bc[tid] = sv;
    }
    __syncthreads();
    if (tid < 16) {
        float bmax = -1e30f;
#pragma unroll
        for (int c = 0; c < 8; ++c) bmax = fmaxf(bmax, bc[c]);
        float e[8]; float es = 0.f;
#pragma unroll
        for (int c = 0; c < 8; ++c) { e[c] = __expf(bc[c] - bmax); es += e[c]; }
        float inv = 1.f / es;
        float sv = 0.f;
#pragma unroll
        for (int c = 0; c < 8; ++c) sv += e[c] * inv * ul[c][tid];
        sjo[tid] = sv;
    }
    __syncthreads();
    if (tid == 0) {
        float sq = 0.f;
#pragma unroll
        for (int oo = 0; oo < 16; ++oo) sq += sjo[oo] * sjo[oo];
        fac[0] = sq / ((1.f + sq) * (sq + 1e-8f));
    }
    __syncthreads();
    if (tid < 16) {
        out[((size_t)n * TC_NCLS + kc) * 16 + tid] = fac[0] * sjo[tid];
    }
}

// ---------------------------------------------------------------------------
extern "C" void kernel_launch(void* const* d_in, const int* in_sizes, int n_in,
                              void* d_out, int out_size, void* d_ws, size_t ws_size,
                              hipStream_t stream) {
    const float* X   = (const float*)d_in[0];
    const float* w1  = (const float*)d_in[1];
    const float* w2  = (const float*)d_in[2];
    const float* wA  = (const float*)d_in[3];
    const float* bA  = (const float*)d_in[4];
    const float* wB  = (const float*)d_in[5];
    const float* bB  = (const float*)d_in[6];
    const float* wk  = (const float*)d_in[7];
    const float* bk  = (const float*)d_in[8];
    const float* Wd  = (const float*)d_in[9];
    const float* alphap = (const float*)d_in[10];
    const float* betap  = (const float*)d_in[11];
    float* out = (float*)d_out;

    float* ws  = (float*)d_ws;
    float* x   = ws;                     // [64][64][1024] = 4194304; reused as vjA
    float* xs  = ws + 4194304;           // [64][64][1024] = 4194304 (squashed in place)
    float* xbS = ws + 8388608;           // [64][8][8][128] = 65536
    float* xB  = ws + 8454144;           // [64][8][128]    = 65536   (8454144..8519680)
    float* xa  = ws + 8519680;           // [32][64][8][1024] = 16777216 (64MB, reused x2)
    float* vjA = x;                      // alias (x dead after k_cellB_conv)

    const size_t need = (size_t)(8519680 + 16777216) * sizeof(float);
    const bool split = ws_size >= need;

    k_conv1<<<dim3(64, 64), 256, 0, stream>>>(X, w1, x);
    k_psim<<<dim3(8, 64), 256, 0, stream>>>(x, w2, xs);
    k_squash_rows<<<dim3(4096), 256, 0, stream>>>(xs);
    k_cellB_conv<<<dim3(8, 64), 256, 0, stream>>>(x, wB, bB, wk, bk, xbS);
    k_routeB<<<dim3(8, 64), 128, 0, stream>>>(xbS, xB);
    if (split) {
        for (int g = 0; g < 2; ++g) {
            k_cellA_conv<<<dim3(16, 32), 256, 0, stream>>>(xs, wA, bA, xa, g * 32);
            k_cellA_route<<<dim3(64, 32), 256, 0, stream>>>(xa, vjA, g * 32);
        }
    } else {
        k_cellA<<<dim3(64, 64), 256, 0, stream>>>(xs, wA, bA, vjA);
    }
    k_digit<<<dim3(10, 64), 256, 0, stream>>>(vjA, xB, Wd, alphap, betap, out);
}

// Round 5
// 377.708 us; speedup vs baseline: 1.5626x; 1.2472x over previous
//
#include <hip/hip_runtime.h>

#define TC_L    1024
#define TC_K    64
#define TC_LN   128
#define TC_NCLS 10
#define TC_DCAT 8320

// ---------------------------------------------------------------------------
// K1: conv1  x[n,k,l] = sum_t w1[k,t] * X[n, l-4+t]   (pad 4)
// grid (k=64, n=64), 256 thr
__global__ __launch_bounds__(256) void k_conv1(
    const float* __restrict__ X, const float* __restrict__ w1, float* __restrict__ x)
{
    const int k = blockIdx.x, n = blockIdx.y;
    float w[9];
#pragma unroll
    for (int t = 0; t < 9; ++t) w[t] = w1[k * 9 + t];
    const float* xin = X + n * TC_L;
    float* out = x + (n * TC_K + k) * TC_L;
    for (int l = threadIdx.x; l < TC_L; l += 256) {
        float acc = 0.f;
#pragma unroll
        for (int t = 0; t < 9; ++t) {
            int idx = l - 4 + t;
            float v = (idx >= 0 && idx < TC_L) ? xin[idx] : 0.f;
            acc = fmaf(w[t], v, acc);
        }
        out[l] = acc;
    }
}

// ---------------------------------------------------------------------------
// K2 (R4): psi_m conv, NO x-staging: direct coalesced global reads, wl in LDS.
// grid (ocb=8, lcq=4, n=64), 256 thr = 64 lgrp x 4 ocg (2 oc each)
__global__ __launch_bounds__(256) void k_psim(
    const float* __restrict__ x, const float* __restrict__ w2, float* __restrict__ xs)
{
    const int ocb = blockIdx.x;
    const int lc  = blockIdx.y * 256;
    const int n   = blockIdx.z;
    __shared__ float wl[8 * 320];     // 10 KB
    const int tid = threadIdx.x;
    for (int i = tid; i < 2560; i += 256) wl[i] = w2[ocb * 2560 + i];
    __syncthreads();

    const int lgrp = tid & 63;
    const int ocg  = tid >> 6;        // wave-uniform
    const int l0   = lgrp * 4;
    const int oc0  = ocg * 2;
    const bool lpad = (lc == 0) && (lgrp == 0);
    const bool rpad = (lc == 768) && (lgrp == 63);

    float acc[2][4] = {};
    const float* xn = x + (size_t)n * TC_K * TC_L;
#pragma unroll 2
    for (int ic = 0; ic < 64; ++ic) {
        const float* row = xn + ic * TC_L + lc;
        float4 va = *(const float4*)&row[l0];                    // l0..l0+3
        float2 vh = *(const float2*)&row[lpad ? l0 : (l0 - 2)];  // l0-2, l0-1
        float2 vb = *(const float2*)&row[l0 + 4];                // l0+4, l0+5
        if (lpad) { vh.x = 0.f; vh.y = 0.f; }
        if (rpad) { vb.x = 0.f; vb.y = 0.f; }
        float v[8] = {vh.x, vh.y, va.x, va.y, va.z, va.w, vb.x, vb.y};
        const float* wp0 = &wl[(oc0 + 0) * 320 + ic * 5];
        const float* wp1 = &wl[(oc0 + 1) * 320 + ic * 5];
#pragma unroll
        for (int t = 0; t < 5; ++t) {
            float w0 = wp0[t], w1 = wp1[t];
#pragma unroll
            for (int j = 0; j < 4; ++j) {
                acc[0][j] = fmaf(w0, v[j + t], acc[0][j]);
                acc[1][j] = fmaf(w1, v[j + t], acc[1][j]);
            }
        }
    }
#pragma unroll
    for (int q = 0; q < 2; ++q) {
        int oc = ocb * 8 + oc0 + q;
        *(float4*)&xs[((size_t)n * TC_K + oc) * TC_L + lc + l0] =
            make_float4(acc[q][0], acc[q][1], acc[q][2], acc[q][3]);
    }
}

// ---------------------------------------------------------------------------
// K3: squash each row of 1024 in place
__global__ __launch_bounds__(256) void k_squash_rows(float* __restrict__ xs)
{
    const int row = blockIdx.x;
    float* p = xs + (size_t)row * TC_L;
    const int tid = threadIdx.x;
    float4 v = *(const float4*)&p[tid * 4];
    float part = v.x * v.x + v.y * v.y + v.z * v.z + v.w * v.w;
    __shared__ float red[256];
    red[tid] = part;
    __syncthreads();
    for (int s = 128; s > 0; s >>= 1) {
        if (tid < s) red[tid] += red[tid + s];
        __syncthreads();
    }
    float sq = red[0];
    float scale = sq / ((1.f + sq) * (sq + 1e-8f));
    v.x *= scale; v.y *= scale; v.z *= scale; v.w *= scale;
    *(float4*)&p[tid * 4] = v;
}

// ---------------------------------------------------------------------------
// K5a: Cell_B convs + bias + squash(last=128) -> xbS[n][j=8][s=8][128]
// grid (s=8, n=64), 256 thr
__global__ __launch_bounds__(256) void k_cellB_conv(
    const float* __restrict__ x, const float* __restrict__ wB, const float* __restrict__ bB,
    const float* __restrict__ wk, const float* __restrict__ bk, float* __restrict__ xbS)
{
    const int s = blockIdx.x;
    const int n = blockIdx.y;
    __shared__ float wBl[64 * 64];    // 16 KB
    __shared__ float wkl[8 * 320];    // 10 KB
    __shared__ float xb1[64][132];    // 33.8 KB  (2-elem zero halo each side)
    __shared__ float redq[8][33];
    const int tid = threadIdx.x;
    for (int i = tid; i < 4096; i += 256) wBl[i] = wB[i];
    for (int i = tid; i < 2560; i += 256) wkl[i] = wk[i];
    for (int i = tid; i < 64; i += 256) {
        xb1[i][0] = xb1[i][1] = xb1[i][130] = xb1[i][131] = 0.f;
    }
    __syncthreads();

    {
        const int t0  = (tid & 31) * 4;   // 0..124
        const int chg = tid >> 5;         // 0..7
        float acc[8][4] = {};
        const float* xbase = x + (size_t)n * TC_K * TC_L + s * TC_LN + t0;
        for (int k = 0; k < 64; ++k) {
            float4 xv = *(const float4*)&xbase[(size_t)k * TC_L];
            float v0 = xv.x, v1 = xv.y, v2 = xv.z, v3 = xv.w;
#pragma unroll
            for (int cc = 0; cc < 8; ++cc) {
                float w = wBl[(chg * 8 + cc) * 64 + k];
                acc[cc][0] = fmaf(w, v0, acc[cc][0]);
                acc[cc][1] = fmaf(w, v1, acc[cc][1]);
                acc[cc][2] = fmaf(w, v2, acc[cc][2]);
                acc[cc][3] = fmaf(w, v3, acc[cc][3]);
            }
        }
#pragma unroll
        for (int cc = 0; cc < 8; ++cc) {
            int ch = chg * 8 + cc;
            float b = bB[ch];
            xb1[ch][2 + t0 + 0] = acc[cc][0] + b;
            xb1[ch][2 + t0 + 1] = acc[cc][1] + b;
            xb1[ch][2 + t0 + 2] = acc[cc][2] + b;
            xb1[ch][2 + t0 + 3] = acc[cc][3] + b;
        }
    }
    __syncthreads();

    {
        const int t0 = (tid & 31) * 4;
        const int j  = tid >> 5;          // 0..7
        float acc[4] = {};
        for (int ch = 0; ch < 64; ++ch) {
            float4 va = *(const float4*)&xb1[ch][t0];
            float4 vb = *(const float4*)&xb1[ch][t0 + 4];
            float v[8] = {va.x, va.y, va.z, va.w, vb.x, vb.y, vb.z, vb.w};
            const float* wp = &wkl[j * 320 + ch * 5];
#pragma unroll
            for (int dw = 0; dw < 5; ++dw) {
                float w = wp[dw];
#pragma unroll
                for (int q = 0; q < 4; ++q) acc[q] = fmaf(w, v[q + dw], acc[q]);
            }
        }
        float b = bk[j];
#pragma unroll
        for (int q = 0; q < 4; ++q) acc[q] += b;
        float part = acc[0]*acc[0] + acc[1]*acc[1] + acc[2]*acc[2] + acc[3]*acc[3];
        redq[j][tid & 31] = part;
        __syncthreads();
        for (int st = 16; st > 0; st >>= 1) {
            if ((tid & 31) < st) redq[j][tid & 31] += redq[j][(tid & 31) + st];
            __syncthreads();
        }
        float sq = redq[j][0];
        float scale = sq / ((1.f + sq) * (sq + 1e-8f));
        float* outp = xbS + (((size_t)n * 8 + j) * 8 + s) * TC_LN + t0;
        *(float4*)outp = make_float4(acc[0]*scale, acc[1]*scale, acc[2]*scale, acc[3]*scale);
    }
}

// ---------------------------------------------------------------------------
// K5b: routing over s for Cell_B -> xB[n][j][t]
__global__ __launch_bounds__(128) void k_routeB(
    const float* __restrict__ xbS, float* __restrict__ xB)
{
    const int j = blockIdx.x, n = blockIdx.y;
    const int t = threadIdx.x;
    float xv[8];
    const float* base = xbS + ((size_t)n * 8 + j) * 8 * TC_LN;
#pragma unroll
    for (int s = 0; s < 8; ++s) xv[s] = base[s * TC_LN + t];

    __shared__ float red[128];
    __shared__ float redp[8][129];

    float sj = 0.f;
#pragma unroll
    for (int s = 0; s < 8; ++s) sj += xv[s];
    sj *= 0.125f;
    red[t] = sj * sj;
    __syncthreads();
    for (int st = 64; st > 0; st >>= 1) { if (t < st) red[t] += red[t + st]; __syncthreads(); }
    float sq = red[0];
    float vfac = sq / ((1.f + sq) * (sq + 1e-8f));
    float vj = vfac * sj;
#pragma unroll
    for (int s = 0; s < 8; ++s) redp[s][t] = xv[s] * vj;
    __syncthreads();
    for (int st = 64; st > 0; st >>= 1) {
        if (t < st) {
#pragma unroll
            for (int s = 0; s < 8; ++s) redp[s][t] += redp[s][t + st];
        }
        __syncthreads();
    }
    float bv[8], bmax = -1e30f;
#pragma unroll
    for (int s = 0; s < 8; ++s) { bv[s] = redp[s][0]; bmax = fmaxf(bmax, bv[s]); }
    float esum = 0.f;
#pragma unroll
    for (int s = 0; s < 8; ++s) { bv[s] = __expf(bv[s] - bmax); esum += bv[s]; }
    float cinv = 1.f / esum;
    float sj2 = 0.f;
#pragma unroll
    for (int s = 0; s < 8; ++s) sj2 += bv[s] * xv[s];
    sj2 *= cinv;
    __syncthreads();
    red[t] = sj2 * sj2;
    __syncthreads();
    for (int st = 64; st > 0; st >>= 1) { if (t < st) red[t] += red[t + st]; __syncthreads(); }
    float sq2 = red[0];
    float vfac2 = sq2 / ((1.f + sq2) * (sq2 + 1e-8f));
    xB[((size_t)n * 8 + j) * TC_LN + t] = vfac2 * sj2;
}

// ---------------------------------------------------------------------------
// K4a: Cell_A conv for all 64 o, one l-chunk of 64, one n.
// grid (16 chunks, 32 n), 256 thr = 16 l-strips x 16 o-groups(4 o each)
__global__ __launch_bounds__(256) void k_cellA_conv(
    const float* __restrict__ xs, const float* __restrict__ wA, const float* __restrict__ bA,
    float* __restrict__ xa, int n0)
{
    const int lc = blockIdx.x * 64;
    const int nrel = blockIdx.y;
    const int n = n0 + nrel;
    const int tid = threadIdx.x;
    __shared__ float xl[64][68];      // cols c=0..65 <-> global l = lc + c - 1
    __shared__ float wl[64 * 24];
    __shared__ float bl[64];
    for (int i = tid; i < 64 * 24; i += 256) wl[i] = wA[i];
    if (tid < 64) bl[tid] = bA[tid];
    const float* xsn = xs + (size_t)n * (TC_K * TC_L);
    for (int i = tid; i < 64 * 66; i += 256) {
        int k = i / 66, c = i - k * 66;
        int gl = lc + c - 1;
        xl[k][c] = (gl >= 0 && gl < TC_L) ? xsn[k * TC_L + gl] : 0.f;
    }
    __syncthreads();

    const int strip = tid & 15;       // l0 = strip*4
    const int g = tid >> 4;           // o = g*4 + oi
    const int l0 = strip * 4;
    float* xab = xa + (size_t)nrel * 64 * 8192;   // [o][p][1024]

#pragma unroll 1
    for (int oi = 0; oi < 4; ++oi) {
        const int o = g * 4 + oi;
        float w[24];
#pragma unroll
        for (int i = 0; i < 24; ++i) w[i] = wl[o * 24 + i];
        const float bias = bl[o];
#pragma unroll
        for (int p = 0; p < 8; ++p) {
            float a0 = bias, a1 = bias, a2 = bias, a3 = bias;
#pragma unroll
            for (int dh = 0; dh < 8; ++dh) {
                const float* row = &xl[p * 8 + dh][l0];
                float4 va = *(const float4*)row;
                float2 vb = *(const float2*)(row + 4);
                float w0 = w[dh * 3], w1 = w[dh * 3 + 1], w2 = w[dh * 3 + 2];
                a0 = fmaf(w0, va.x, a0); a0 = fmaf(w1, va.y, a0); a0 = fmaf(w2, va.z, a0);
                a1 = fmaf(w0, va.y, a1); a1 = fmaf(w1, va.z, a1); a1 = fmaf(w2, va.w, a1);
                a2 = fmaf(w0, va.z, a2); a2 = fmaf(w1, va.w, a2); a2 = fmaf(w2, vb.x, a2);
                a3 = fmaf(w0, va.w, a3); a3 = fmaf(w1, vb.x, a3); a3 = fmaf(w2, vb.y, a3);
            }
            *(float4*)&xab[(size_t)o * 8192 + p * TC_L + lc + l0] = make_float4(a0, a1, a2, a3);
        }
    }
}

// ---------------------------------------------------------------------------
// K4b: routing over p from xa (contiguous 32KB per (n,o)), coalesced loads.
// grid (o=64, 32 n), 256 thr
__global__ __launch_bounds__(256) void k_cellA_route(
    const float* __restrict__ xa, float* __restrict__ vjA, int n0)
{
    const int o = blockIdx.x;
    const int nrel = blockIdx.y;
    const int n = n0 + nrel;
    const int tid = threadIdx.x;
    const int l0 = tid * 4;
    const float* base = xa + ((size_t)nrel * 64 + o) * 8192;

    float xrv[8][4];
#pragma unroll
    for (int p = 0; p < 8; ++p) {
        float4 v = *(const float4*)&base[p * TC_L + l0];
        xrv[p][0] = v.x; xrv[p][1] = v.y; xrv[p][2] = v.z; xrv[p][3] = v.w;
    }

    __shared__ float red[256];
    __shared__ float redp[8][257];

    float sjv[4];
    float part = 0.f;
#pragma unroll
    for (int jj = 0; jj < 4; ++jj) {
        float sv = 0.f;
#pragma unroll
        for (int p = 0; p < 8; ++p) sv += xrv[p][jj];
        sv *= 0.125f;
        sjv[jj] = sv;
        part += sv * sv;
    }
    red[tid] = part;
    __syncthreads();
    for (int st = 128; st > 0; st >>= 1) { if (tid < st) red[tid] += red[tid + st]; __syncthreads(); }
    float sq = red[0];
    float vfac = sq / ((1.f + sq) * (sq + 1e-8f));
    float bp[8] = {};
#pragma unroll
    for (int jj = 0; jj < 4; ++jj) {
        float vj = vfac * sjv[jj];
#pragma unroll
        for (int p = 0; p < 8; ++p) bp[p] += xrv[p][jj] * vj;
    }
#pragma unroll
    for (int p = 0; p < 8; ++p) redp[p][tid] = bp[p];
    __syncthreads();
    for (int st = 128; st > 0; st >>= 1) {
        if (tid < st) {
#pragma unroll
            for (int p = 0; p < 8; ++p) redp[p][tid] += redp[p][tid + st];
        }
        __syncthreads();
    }
    float bv[8], bmax = -1e30f;
#pragma unroll
    for (int p = 0; p < 8; ++p) { bv[p] = redp[p][0]; bmax = fmaxf(bmax, bv[p]); }
    float esum = 0.f;
#pragma unroll
    for (int p = 0; p < 8; ++p) { bv[p] = __expf(bv[p] - bmax); esum += bv[p]; }
    float cinv = 1.f / esum;
    float sj2[4]; float part2 = 0.f;
#pragma unroll
    for (int jj = 0; jj < 4; ++jj) {
        float sv = 0.f;
#pragma unroll
        for (int p = 0; p < 8; ++p) sv += bv[p] * xrv[p][jj];
        sv *= cinv;
        sj2[jj] = sv;
        part2 += sv * sv;
    }
    __syncthreads();
    red[tid] = part2;
    __syncthreads();
    for (int st = 128; st > 0; st >>= 1) { if (tid < st) red[tid] += red[tid + st]; __syncthreads(); }
    float sq2 = red[0];
    float vfac2 = sq2 / ((1.f + sq2) * (sq2 + 1e-8f));
    float* outp = vjA + ((size_t)n * 64 + o) * TC_L + l0;
    *(float4*)outp = make_float4(vfac2*sj2[0], vfac2*sj2[1], vfac2*sj2[2], vfac2*sj2[3]);
}

// ---------------------------------------------------------------------------
// K4 (fallback): fused Cell_A — used only if ws too small for xa.
__global__ __launch_bounds__(256, 4) void k_cellA(
    const float* __restrict__ xs, const float* __restrict__ wA, const float* __restrict__ bA,
    float* __restrict__ vjA)
{
    const int o = blockIdx.x;
    const int n = blockIdx.y;
    const int tid = threadIdx.x;
    const int l0 = tid * 4;

    float w[24];
#pragma unroll
    for (int i = 0; i < 24; ++i) w[i] = wA[o * 24 + i];
    const float bias = bA[o];

    const float* xsn = xs + (size_t)n * TC_K * TC_L;
    float xrv[8][4];
#pragma unroll 1
    for (int p = 0; p < 8; ++p) {
        float a0 = bias, a1 = bias, a2 = bias, a3 = bias;
#pragma unroll
        for (int dh = 0; dh < 8; ++dh) {
            const float* row = xsn + (p * 8 + dh) * TC_L;
            float4 vm = *(const float4*)&row[l0];
            float vl = (l0 > 0) ? row[l0 - 1] : 0.f;
            float vr = (l0 + 4 < TC_L) ? row[l0 + 4] : 0.f;
            float w0 = w[dh * 3 + 0], w1 = w[dh * 3 + 1], w2 = w[dh * 3 + 2];
            a0 = fmaf(w0, vl,   a0); a0 = fmaf(w1, vm.x, a0); a0 = fmaf(w2, vm.y, a0);
            a1 = fmaf(w0, vm.x, a1); a1 = fmaf(w1, vm.y, a1); a1 = fmaf(w2, vm.z, a1);
            a2 = fmaf(w0, vm.y, a2); a2 = fmaf(w1, vm.z, a2); a2 = fmaf(w2, vm.w, a2);
            a3 = fmaf(w0, vm.z, a3); a3 = fmaf(w1, vm.w, a3); a3 = fmaf(w2, vr,   a3);
        }
        xrv[p][0] = a0; xrv[p][1] = a1; xrv[p][2] = a2; xrv[p][3] = a3;
    }

    __shared__ float red[256];
    __shared__ float redp[8][257];

    float sjv[4];
    float part = 0.f;
#pragma unroll
    for (int jj = 0; jj < 4; ++jj) {
        float sv = 0.f;
#pragma unroll
        for (int p = 0; p < 8; ++p) sv += xrv[p][jj];
        sv *= 0.125f;
        sjv[jj] = sv;
        part += sv * sv;
    }
    red[tid] = part;
    __syncthreads();
    for (int st = 128; st > 0; st >>= 1) { if (tid < st) red[tid] += red[tid + st]; __syncthreads(); }
    float sq = red[0];
    float vfac = sq / ((1.f + sq) * (sq + 1e-8f));
    float bp[8] = {};
#pragma unroll
    for (int jj = 0; jj < 4; ++jj) {
        float vj = vfac * sjv[jj];
#pragma unroll
        for (int p = 0; p < 8; ++p) bp[p] += xrv[p][jj] * vj;
    }
#pragma unroll
    for (int p = 0; p < 8; ++p) redp[p][tid] = bp[p];
    __syncthreads();
    for (int st = 128; st > 0; st >>= 1) {
        if (tid < st) {
#pragma unroll
            for (int p = 0; p < 8; ++p) redp[p][tid] += redp[p][tid + st];
        }
        __syncthreads();
    }
    float bv[8], bmax = -1e30f;
#pragma unroll
    for (int p = 0; p < 8; ++p) { bv[p] = redp[p][0]; bmax = fmaxf(bmax, bv[p]); }
    float esum = 0.f;
#pragma unroll
    for (int p = 0; p < 8; ++p) { bv[p] = __expf(bv[p] - bmax); esum += bv[p]; }
    float cinv = 1.f / esum;
    float sj2[4]; float part2 = 0.f;
#pragma unroll
    for (int jj = 0; jj < 4; ++jj) {
        float sv = 0.f;
#pragma unroll
        for (int p = 0; p < 8; ++p) sv += bv[p] * xrv[p][jj];
        sv *= cinv;
        sj2[jj] = sv;
        part2 += sv * sv;
    }
    __syncthreads();
    red[tid] = part2;
    __syncthreads();
    for (int st = 128; st > 0; st >>= 1) { if (tid < st) red[tid] += red[tid + st]; __syncthreads(); }
    float sq2 = red[0];
    float vfac2 = sq2 / ((1.f + sq2) * (sq2 + 1e-8f));
    float* outp = vjA + ((size_t)n * 64 + o) * TC_L + l0;
    *(float4*)outp = make_float4(vfac2*sj2[0], vfac2*sj2[1], vfac2*sj2[2], vfac2*sj2[3]);
}

// ---------------------------------------------------------------------------
// K6 (R4): DigitCaps rewrite. 256 thr = 64 d-lanes x 4 o-quads.
// W read as float4 (contiguous 1KB per wave); x staged transposed xT[8][520]
// (broadcast, conflict-free reads); acc[8][4] in registers; one end reduction.
__global__ __launch_bounds__(256) void k_digit(
    const float* __restrict__ vjA, const float* __restrict__ xB,
    const float* __restrict__ W, const float* __restrict__ alphap,
    const float* __restrict__ betap, float* __restrict__ out)
{
    const int kc = blockIdx.x;
    const int n = blockIdx.y;
    const int tid = threadIdx.x;
    const int dl = tid >> 2;     // 0..63
    const int oq = tid & 3;      // 0..3  -> o = oq*4 + j
    const float alpha = alphap[0], beta = betap[0];

    __shared__ float smem[8448];   // 33 KB: xT[8][520] during GEMM; red[64][132] after
    __shared__ float ul[8][16];
    __shared__ float sjo[16];
    __shared__ float bc[8];
    __shared__ float fac[1];

    float acc[8][4] = {};
    const float* vjAn = vjA + (size_t)n * 65536;
    const float* xBn  = xB  + (size_t)n * 1024;
    const float* Wk   = W   + (size_t)kc * (TC_DCAT * 16);

    for (int d0 = 0; d0 < TC_DCAT; d0 += 512) {
        __syncthreads();
        for (int i = tid; i < 4096; i += 256) {
            int c = i >> 9, dd = i & 511, d = d0 + dd;
            float v = 0.f;
            if (d < 8192) v = alpha * vjAn[c * 8192 + d];
            else if (d < TC_DCAT) v = beta * xBn[c * 128 + (d - 8192)];
            smem[c * 520 + dd] = v;
        }
        __syncthreads();
#pragma unroll 4
        for (int it = 0; it < 8; ++it) {
            int dd = it * 64 + dl;
            int d = d0 + dd;
            int cl = d < TC_DCAT ? d : (TC_DCAT - 1);   // xT=0 there nullifies
            float4 wv = *(const float4*)&Wk[(size_t)cl * 16 + oq * 4];
#pragma unroll
            for (int c = 0; c < 8; ++c) {
                float xv = smem[c * 520 + dd];
                acc[c][0] = fmaf(wv.x, xv, acc[c][0]);
                acc[c][1] = fmaf(wv.y, xv, acc[c][1]);
                acc[c][2] = fmaf(wv.z, xv, acc[c][2]);
                acc[c][3] = fmaf(wv.w, xv, acc[c][3]);
            }
        }
    }

    __syncthreads();
#pragma unroll
    for (int c = 0; c < 8; ++c)
        *(float4*)&smem[dl * 132 + c * 16 + oq * 4] =
            make_float4(acc[c][0], acc[c][1], acc[c][2], acc[c][3]);
    __syncthreads();
    if (tid < 128) {
        int c = tid >> 4, o = tid & 15;
        float sv = 0.f;
        for (int q = 0; q < 64; ++q) sv += smem[q * 132 + c * 16 + o];
        ul[c][o] = sv;
    }
    __syncthreads();

    // routing iter 1
    if (tid < 16) {
        float sv = 0.f;
#pragma unroll
        for (int c = 0; c < 8; ++c) sv += ul[c][tid];
        sjo[tid] = sv * 0.125f;
    }
    __syncthreads();
    if (tid == 0) {
        float sq = 0.f;
#pragma unroll
        for (int oo = 0; oo < 16; ++oo) sq += sjo[oo] * sjo[oo];
        fac[0] = sq / ((1.f + sq) * (sq + 1e-8f));
    }
    __syncthreads();
    if (tid < 8) {
        float vf = fac[0];
        float sv = 0.f;
#pragma unroll
        for (int oo = 0; oo < 16; ++oo) sv += ul[tid][oo] * (vf * sjo[oo]);
        bc[tid] = sv;
    }
    __syncthreads();
    // iter 2
    if (tid < 16) {
        float bmax = -1e30f;
#pragma unroll
        for (int c = 0; c < 8; ++c) bmax = fmaxf(bmax, bc[c]);
        float e[8]; float es = 0.f;
#pragma unroll
        for (int c = 0; c < 8; ++c) { e[c] = __expf(bc[c] - bmax); es += e[c]; }
        float inv = 1.f / es;
        float sv = 0.f;
#pragma unroll
        for (int c = 0; c < 8; ++c) sv += e[c] * inv * ul[c][tid];
        sjo[tid] = sv;
    }
    __syncthreads();
    if (tid == 0) {
        float sq = 0.f;
#pragma unroll
        for (int oo = 0; oo < 16; ++oo) sq += sjo[oo] * sjo[oo];
        fac[0] = sq / ((1.f + sq) * (sq + 1e-8f));
    }
    __syncthreads();
    if (tid < 16) {
        out[((size_t)n * TC_NCLS + kc) * 16 + tid] = fac[0] * sjo[tid];
    }
}

// ---------------------------------------------------------------------------
extern "C" void kernel_launch(void* const* d_in, const int* in_sizes, int n_in,
                              void* d_out, int out_size, void* d_ws, size_t ws_size,
                              hipStream_t stream) {
    const float* X   = (const float*)d_in[0];
    const float* w1  = (const float*)d_in[1];
    const float* w2  = (const float*)d_in[2];
    const float* wA  = (const float*)d_in[3];
    const float* bA  = (const float*)d_in[4];
    const float* wB  = (const float*)d_in[5];
    const float* bB  = (const float*)d_in[6];
    const float* wk  = (const float*)d_in[7];
    const float* bk  = (const float*)d_in[8];
    const float* Wd  = (const float*)d_in[9];
    const float* alphap = (const float*)d_in[10];
    const float* betap  = (const float*)d_in[11];
    float* out = (float*)d_out;

    float* ws  = (float*)d_ws;
    float* x   = ws;                     // [64][64][1024] = 4194304; reused as vjA
    float* xs  = ws + 4194304;           // [64][64][1024] = 4194304 (squashed in place)
    float* xbS = ws + 8388608;           // [64][8][8][128] = 65536
    float* xB  = ws + 8454144;           // [64][8][128]    = 65536 region (8454144..8519680)
    float* xa  = ws + 8519680;           // [32][64][8][1024] = 16777216 (64MB, reused x2)
    float* vjA = x;                      // alias (x dead after k_cellB_conv)

    const size_t need = (size_t)(8519680 + 16777216) * sizeof(float);
    const bool split = ws_size >= need;

    k_conv1<<<dim3(64, 64), 256, 0, stream>>>(X, w1, x);
    k_psim<<<dim3(8, 4, 64), 256, 0, stream>>>(x, w2, xs);
    k_squash_rows<<<dim3(4096), 256, 0, stream>>>(xs);
    k_cellB_conv<<<dim3(8, 64), 256, 0, stream>>>(x, wB, bB, wk, bk, xbS);
    k_routeB<<<dim3(8, 64), 128, 0, stream>>>(xbS, xB);
    if (split) {
        for (int g = 0; g < 2; ++g) {
            k_cellA_conv<<<dim3(16, 32), 256, 0, stream>>>(xs, wA, bA, xa, g * 32);
            k_cellA_route<<<dim3(64, 32), 256, 0, stream>>>(xa, vjA, g * 32);
        }
    } else {
        k_cellA<<<dim3(64, 64), 256, 0, stream>>>(xs, wA, bA, vjA);
    }
    k_digit<<<dim3(10, 64), 256, 0, stream>>>(vjA, xB, Wd, alphap, betap, out);
}

// Round 6
// 316.626 us; speedup vs baseline: 1.8641x; 1.1929x over previous
//
#include <hip/hip_runtime.h>

#define TC_L    1024
#define TC_K    64
#define TC_LN   128
#define TC_NCLS 10
#define TC_DCAT 8320

// ---------------------------------------------------------------------------
// K1: conv1  x[n,k,l] = sum_t w1[k,t] * X[n, l-4+t]   (pad 4)
// grid (k=64, n=64), 256 thr
__global__ __launch_bounds__(256) void k_conv1(
    const float* __restrict__ X, const float* __restrict__ w1, float* __restrict__ x)
{
    const int k = blockIdx.x, n = blockIdx.y;
    float w[9];
#pragma unroll
    for (int t = 0; t < 9; ++t) w[t] = w1[k * 9 + t];
    const float* xin = X + n * TC_L;
    float* out = x + (n * TC_K + k) * TC_L;
    for (int l = threadIdx.x; l < TC_L; l += 256) {
        float acc = 0.f;
#pragma unroll
        for (int t = 0; t < 9; ++t) {
            int idx = l - 4 + t;
            float v = (idx >= 0 && idx < TC_L) ? xin[idx] : 0.f;
            acc = fmaf(w[t], v, acc);
        }
        out[l] = acc;
    }
}

// ---------------------------------------------------------------------------
// K2: psi_m conv, direct coalesced global reads, weights in LDS.
// grid (ocb=8, lcq=4, n=64), 256 thr = 64 lgrp x 4 ocg (2 oc each)
__global__ __launch_bounds__(256) void k_psim(
    const float* __restrict__ x, const float* __restrict__ w2, float* __restrict__ xs)
{
    const int ocb = blockIdx.x;
    const int lc  = blockIdx.y * 256;
    const int n   = blockIdx.z;
    __shared__ float wl[8 * 320];     // 10 KB
    const int tid = threadIdx.x;
    for (int i = tid; i < 2560; i += 256) wl[i] = w2[ocb * 2560 + i];
    __syncthreads();

    const int lgrp = tid & 63;
    const int ocg  = tid >> 6;        // wave-uniform
    const int l0   = lgrp * 4;
    const int oc0  = ocg * 2;
    const bool lpad = (lc == 0) && (lgrp == 0);
    const bool rpad = (lc == 768) && (lgrp == 63);

    float acc[2][4] = {};
    const float* xn = x + (size_t)n * TC_K * TC_L;
#pragma unroll 2
    for (int ic = 0; ic < 64; ++ic) {
        const float* row = xn + ic * TC_L + lc;
        float4 va = *(const float4*)&row[l0];                    // l0..l0+3
        float2 vh = *(const float2*)&row[lpad ? l0 : (l0 - 2)];  // l0-2, l0-1
        float2 vb = *(const float2*)&row[l0 + 4];                // l0+4, l0+5
        if (lpad) { vh.x = 0.f; vh.y = 0.f; }
        if (rpad) { vb.x = 0.f; vb.y = 0.f; }
        float v[8] = {vh.x, vh.y, va.x, va.y, va.z, va.w, vb.x, vb.y};
        const float* wp0 = &wl[(oc0 + 0) * 320 + ic * 5];
        const float* wp1 = &wl[(oc0 + 1) * 320 + ic * 5];
#pragma unroll
        for (int t = 0; t < 5; ++t) {
            float w0 = wp0[t], w1 = wp1[t];
#pragma unroll
            for (int j = 0; j < 4; ++j) {
                acc[0][j] = fmaf(w0, v[j + t], acc[0][j]);
                acc[1][j] = fmaf(w1, v[j + t], acc[1][j]);
            }
        }
    }
#pragma unroll
    for (int q = 0; q < 2; ++q) {
        int oc = ocb * 8 + oc0 + q;
        *(float4*)&xs[((size_t)n * TC_K + oc) * TC_L + lc + l0] =
            make_float4(acc[q][0], acc[q][1], acc[q][2], acc[q][3]);
    }
}

// ---------------------------------------------------------------------------
// K3: squash each row of 1024 in place
__global__ __launch_bounds__(256) void k_squash_rows(float* __restrict__ xs)
{
    const int row = blockIdx.x;
    float* p = xs + (size_t)row * TC_L;
    const int tid = threadIdx.x;
    float4 v = *(const float4*)&p[tid * 4];
    float part = v.x * v.x + v.y * v.y + v.z * v.z + v.w * v.w;
    __shared__ float red[256];
    red[tid] = part;
    __syncthreads();
    for (int s = 128; s > 0; s >>= 1) {
        if (tid < s) red[tid] += red[tid + s];
        __syncthreads();
    }
    float sq = red[0];
    float scale = sq / ((1.f + sq) * (sq + 1e-8f));
    v.x *= scale; v.y *= scale; v.z *= scale; v.w *= scale;
    *(float4*)&p[tid * 4] = v;
}

// ---------------------------------------------------------------------------
// K5a: Cell_B convs + bias + squash(last=128) -> xbS[n][j=8][s=8][128]
// grid (s=8, n=64), 256 thr
__global__ __launch_bounds__(256) void k_cellB_conv(
    const float* __restrict__ x, const float* __restrict__ wB, const float* __restrict__ bB,
    const float* __restrict__ wk, const float* __restrict__ bk, float* __restrict__ xbS)
{
    const int s = blockIdx.x;
    const int n = blockIdx.y;
    __shared__ float wBl[64 * 64];    // 16 KB
    __shared__ float wkl[8 * 320];    // 10 KB
    __shared__ float xb1[64][132];    // 33.8 KB  (2-elem zero halo each side)
    __shared__ float redq[8][33];
    const int tid = threadIdx.x;
    for (int i = tid; i < 4096; i += 256) wBl[i] = wB[i];
    for (int i = tid; i < 2560; i += 256) wkl[i] = wk[i];
    for (int i = tid; i < 64; i += 256) {
        xb1[i][0] = xb1[i][1] = xb1[i][130] = xb1[i][131] = 0.f;
    }
    __syncthreads();

    {
        const int t0  = (tid & 31) * 4;   // 0..124
        const int chg = tid >> 5;         // 0..7
        float acc[8][4] = {};
        const float* xbase = x + (size_t)n * TC_K * TC_L + s * TC_LN + t0;
        for (int k = 0; k < 64; ++k) {
            float4 xv = *(const float4*)&xbase[(size_t)k * TC_L];
            float v0 = xv.x, v1 = xv.y, v2 = xv.z, v3 = xv.w;
#pragma unroll
            for (int cc = 0; cc < 8; ++cc) {
                float w = wBl[(chg * 8 + cc) * 64 + k];
                acc[cc][0] = fmaf(w, v0, acc[cc][0]);
                acc[cc][1] = fmaf(w, v1, acc[cc][1]);
                acc[cc][2] = fmaf(w, v2, acc[cc][2]);
                acc[cc][3] = fmaf(w, v3, acc[cc][3]);
            }
        }
#pragma unroll
        for (int cc = 0; cc < 8; ++cc) {
            int ch = chg * 8 + cc;
            float b = bB[ch];
            xb1[ch][2 + t0 + 0] = acc[cc][0] + b;
            xb1[ch][2 + t0 + 1] = acc[cc][1] + b;
            xb1[ch][2 + t0 + 2] = acc[cc][2] + b;
            xb1[ch][2 + t0 + 3] = acc[cc][3] + b;
        }
    }
    __syncthreads();

    {
        const int t0 = (tid & 31) * 4;
        const int j  = tid >> 5;          // 0..7
        float acc[4] = {};
        for (int ch = 0; ch < 64; ++ch) {
            float4 va = *(const float4*)&xb1[ch][t0];
            float4 vb = *(const float4*)&xb1[ch][t0 + 4];
            float v[8] = {va.x, va.y, va.z, va.w, vb.x, vb.y, vb.z, vb.w};
            const float* wp = &wkl[j * 320 + ch * 5];
#pragma unroll
            for (int dw = 0; dw < 5; ++dw) {
                float w = wp[dw];
#pragma unroll
                for (int q = 0; q < 4; ++q) acc[q] = fmaf(w, v[q + dw], acc[q]);
            }
        }
        float b = bk[j];
#pragma unroll
        for (int q = 0; q < 4; ++q) acc[q] += b;
        float part = acc[0]*acc[0] + acc[1]*acc[1] + acc[2]*acc[2] + acc[3]*acc[3];
        redq[j][tid & 31] = part;
        __syncthreads();
        for (int st = 16; st > 0; st >>= 1) {
            if ((tid & 31) < st) redq[j][tid & 31] += redq[j][(tid & 31) + st];
            __syncthreads();
        }
        float sq = redq[j][0];
        float scale = sq / ((1.f + sq) * (sq + 1e-8f));
        float* outp = xbS + (((size_t)n * 8 + j) * 8 + s) * TC_LN + t0;
        *(float4*)outp = make_float4(acc[0]*scale, acc[1]*scale, acc[2]*scale, acc[3]*scale);
    }
}

// ---------------------------------------------------------------------------
// K5b: routing over s for Cell_B -> xB[n][j][t]
__global__ __launch_bounds__(128) void k_routeB(
    const float* __restrict__ xbS, float* __restrict__ xB)
{
    const int j = blockIdx.x, n = blockIdx.y;
    const int t = threadIdx.x;
    float xv[8];
    const float* base = xbS + ((size_t)n * 8 + j) * 8 * TC_LN;
#pragma unroll
    for (int s = 0; s < 8; ++s) xv[s] = base[s * TC_LN + t];

    __shared__ float red[128];
    __shared__ float redp[8][129];

    float sj = 0.f;
#pragma unroll
    for (int s = 0; s < 8; ++s) sj += xv[s];
    sj *= 0.125f;
    red[t] = sj * sj;
    __syncthreads();
    for (int st = 64; st > 0; st >>= 1) { if (t < st) red[t] += red[t + st]; __syncthreads(); }
    float sq = red[0];
    float vfac = sq / ((1.f + sq) * (sq + 1e-8f));
    float vj = vfac * sj;
#pragma unroll
    for (int s = 0; s < 8; ++s) redp[s][t] = xv[s] * vj;
    __syncthreads();
    for (int st = 64; st > 0; st >>= 1) {
        if (t < st) {
#pragma unroll
            for (int s = 0; s < 8; ++s) redp[s][t] += redp[s][t + st];
        }
        __syncthreads();
    }
    float bv[8], bmax = -1e30f;
#pragma unroll
    for (int s = 0; s < 8; ++s) { bv[s] = redp[s][0]; bmax = fmaxf(bmax, bv[s]); }
    float esum = 0.f;
#pragma unroll
    for (int s = 0; s < 8; ++s) { bv[s] = __expf(bv[s] - bmax); esum += bv[s]; }
    float cinv = 1.f / esum;
    float sj2 = 0.f;
#pragma unroll
    for (int s = 0; s < 8; ++s) sj2 += bv[s] * xv[s];
    sj2 *= cinv;
    __syncthreads();
    red[t] = sj2 * sj2;
    __syncthreads();
    for (int st = 64; st > 0; st >>= 1) { if (t < st) red[t] += red[t + st]; __syncthreads(); }
    float sq2 = red[0];
    float vfac2 = sq2 / ((1.f + sq2) * (sq2 + 1e-8f));
    xB[((size_t)n * 8 + j) * TC_LN + t] = vfac2 * sj2;
}

// ---------------------------------------------------------------------------
// K4a: Cell_A conv for all 64 o, one l-chunk of 64, one n.
// grid (16 chunks, 32 n), 256 thr = 16 l-strips x 16 o-groups(4 o each)
__global__ __launch_bounds__(256) void k_cellA_conv(
    const float* __restrict__ xs, const float* __restrict__ wA, const float* __restrict__ bA,
    float* __restrict__ xa, int n0)
{
    const int lc = blockIdx.x * 64;
    const int nrel = blockIdx.y;
    const int n = n0 + nrel;
    const int tid = threadIdx.x;
    __shared__ float xl[64][68];      // cols c=0..65 <-> global l = lc + c - 1
    __shared__ float wl[64 * 24];
    __shared__ float bl[64];
    for (int i = tid; i < 64 * 24; i += 256) wl[i] = wA[i];
    if (tid < 64) bl[tid] = bA[tid];
    const float* xsn = xs + (size_t)n * (TC_K * TC_L);
    for (int i = tid; i < 64 * 66; i += 256) {
        int k = i / 66, c = i - k * 66;
        int gl = lc + c - 1;
        xl[k][c] = (gl >= 0 && gl < TC_L) ? xsn[k * TC_L + gl] : 0.f;
    }
    __syncthreads();

    const int strip = tid & 15;       // l0 = strip*4
    const int g = tid >> 4;           // o = g*4 + oi
    const int l0 = strip * 4;
    float* xab = xa + (size_t)nrel * 64 * 8192;   // [o][p][1024]

#pragma unroll 1
    for (int oi = 0; oi < 4; ++oi) {
        const int o = g * 4 + oi;
        float w[24];
#pragma unroll
        for (int i = 0; i < 24; ++i) w[i] = wl[o * 24 + i];
        const float bias = bl[o];
#pragma unroll
        for (int p = 0; p < 8; ++p) {
            float a0 = bias, a1 = bias, a2 = bias, a3 = bias;
#pragma unroll
            for (int dh = 0; dh < 8; ++dh) {
                const float* row = &xl[p * 8 + dh][l0];
                float4 va = *(const float4*)row;
                float2 vb = *(const float2*)(row + 4);
                float w0 = w[dh * 3], w1 = w[dh * 3 + 1], w2 = w[dh * 3 + 2];
                a0 = fmaf(w0, va.x, a0); a0 = fmaf(w1, va.y, a0); a0 = fmaf(w2, va.z, a0);
                a1 = fmaf(w0, va.y, a1); a1 = fmaf(w1, va.z, a1); a1 = fmaf(w2, va.w, a1);
                a2 = fmaf(w0, va.z, a2); a2 = fmaf(w1, va.w, a2); a2 = fmaf(w2, vb.x, a2);
                a3 = fmaf(w0, va.w, a3); a3 = fmaf(w1, vb.x, a3); a3 = fmaf(w2, vb.y, a3);
            }
            *(float4*)&xab[(size_t)o * 8192 + p * TC_L + lc + l0] = make_float4(a0, a1, a2, a3);
        }
    }
}

// ---------------------------------------------------------------------------
// K4b: routing over p from xa (contiguous 32KB per (n,o)), coalesced loads.
// grid (o=64, 32 n), 256 thr
__global__ __launch_bounds__(256) void k_cellA_route(
    const float* __restrict__ xa, float* __restrict__ vjA, int n0)
{
    const int o = blockIdx.x;
    const int nrel = blockIdx.y;
    const int n = n0 + nrel;
    const int tid = threadIdx.x;
    const int l0 = tid * 4;
    const float* base = xa + ((size_t)nrel * 64 + o) * 8192;

    float xrv[8][4];
#pragma unroll
    for (int p = 0; p < 8; ++p) {
        float4 v = *(const float4*)&base[p * TC_L + l0];
        xrv[p][0] = v.x; xrv[p][1] = v.y; xrv[p][2] = v.z; xrv[p][3] = v.w;
    }

    __shared__ float red[256];
    __shared__ float redp[8][257];

    float sjv[4];
    float part = 0.f;
#pragma unroll
    for (int jj = 0; jj < 4; ++jj) {
        float sv = 0.f;
#pragma unroll
        for (int p = 0; p < 8; ++p) sv += xrv[p][jj];
        sv *= 0.125f;
        sjv[jj] = sv;
        part += sv * sv;
    }
    red[tid] = part;
    __syncthreads();
    for (int st = 128; st > 0; st >>= 1) { if (tid < st) red[tid] += red[tid + st]; __syncthreads(); }
    float sq = red[0];
    float vfac = sq / ((1.f + sq) * (sq + 1e-8f));
    float bp[8] = {};
#pragma unroll
    for (int jj = 0; jj < 4; ++jj) {
        float vj = vfac * sjv[jj];
#pragma unroll
        for (int p = 0; p < 8; ++p) bp[p] += xrv[p][jj] * vj;
    }
#pragma unroll
    for (int p = 0; p < 8; ++p) redp[p][tid] = bp[p];
    __syncthreads();
    for (int st = 128; st > 0; st >>= 1) {
        if (tid < st) {
#pragma unroll
            for (int p = 0; p < 8; ++p) redp[p][tid] += redp[p][tid + st];
        }
        __syncthreads();
    }
    float bv[8], bmax = -1e30f;
#pragma unroll
    for (int p = 0; p < 8; ++p) { bv[p] = redp[p][0]; bmax = fmaxf(bmax, bv[p]); }
    float esum = 0.f;
#pragma unroll
    for (int p = 0; p < 8; ++p) { bv[p] = __expf(bv[p] - bmax); esum += bv[p]; }
    float cinv = 1.f / esum;
    float sj2[4]; float part2 = 0.f;
#pragma unroll
    for (int jj = 0; jj < 4; ++jj) {
        float sv = 0.f;
#pragma unroll
        for (int p = 0; p < 8; ++p) sv += bv[p] * xrv[p][jj];
        sv *= cinv;
        sj2[jj] = sv;
        part2 += sv * sv;
    }
    __syncthreads();
    red[tid] = part2;
    __syncthreads();
    for (int st = 128; st > 0; st >>= 1) { if (tid < st) red[tid] += red[tid + st]; __syncthreads(); }
    float sq2 = red[0];
    float vfac2 = sq2 / ((1.f + sq2) * (sq2 + 1e-8f));
    float* outp = vjA + ((size_t)n * 64 + o) * TC_L + l0;
    *(float4*)outp = make_float4(vfac2*sj2[0], vfac2*sj2[1], vfac2*sj2[2], vfac2*sj2[3]);
}

// ---------------------------------------------------------------------------
// K4 (fallback): fused Cell_A — used only if ws too small for xa.
__global__ __launch_bounds__(256, 4) void k_cellA(
    const float* __restrict__ xs, const float* __restrict__ wA, const float* __restrict__ bA,
    float* __restrict__ vjA)
{
    const int o = blockIdx.x;
    const int n = blockIdx.y;
    const int tid = threadIdx.x;
    const int l0 = tid * 4;

    float w[24];
#pragma unroll
    for (int i = 0; i < 24; ++i) w[i] = wA[o * 24 + i];
    const float bias = bA[o];

    const float* xsn = xs + (size_t)n * TC_K * TC_L;
    float xrv[8][4];
#pragma unroll 1
    for (int p = 0; p < 8; ++p) {
        float a0 = bias, a1 = bias, a2 = bias, a3 = bias;
#pragma unroll
        for (int dh = 0; dh < 8; ++dh) {
            const float* row = xsn + (p * 8 + dh) * TC_L;
            float4 vm = *(const float4*)&row[l0];
            float vl = (l0 > 0) ? row[l0 - 1] : 0.f;
            float vr = (l0 + 4 < TC_L) ? row[l0 + 4] : 0.f;
            float w0 = w[dh * 3 + 0], w1 = w[dh * 3 + 1], w2 = w[dh * 3 + 2];
            a0 = fmaf(w0, vl,   a0); a0 = fmaf(w1, vm.x, a0); a0 = fmaf(w2, vm.y, a0);
            a1 = fmaf(w0, vm.x, a1); a1 = fmaf(w1, vm.y, a1); a1 = fmaf(w2, vm.z, a1);
            a2 = fmaf(w0, vm.y, a2); a2 = fmaf(w1, vm.z, a2); a2 = fmaf(w2, vm.w, a2);
            a3 = fmaf(w0, vm.z, a3); a3 = fmaf(w1, vm.w, a3); a3 = fmaf(w2, vr,   a3);
        }
        xrv[p][0] = a0; xrv[p][1] = a1; xrv[p][2] = a2; xrv[p][3] = a3;
    }

    __shared__ float red[256];
    __shared__ float redp[8][257];

    float sjv[4];
    float part = 0.f;
#pragma unroll
    for (int jj = 0; jj < 4; ++jj) {
        float sv = 0.f;
#pragma unroll
        for (int p = 0; p < 8; ++p) sv += xrv[p][jj];
        sv *= 0.125f;
        sjv[jj] = sv;
        part += sv * sv;
    }
    red[tid] = part;
    __syncthreads();
    for (int st = 128; st > 0; st >>= 1) { if (tid < st) red[tid] += red[tid + st]; __syncthreads(); }
    float sq = red[0];
    float vfac = sq / ((1.f + sq) * (sq + 1e-8f));
    float bp[8] = {};
#pragma unroll
    for (int jj = 0; jj < 4; ++jj) {
        float vj = vfac * sjv[jj];
#pragma unroll
        for (int p = 0; p < 8; ++p) bp[p] += xrv[p][jj] * vj;
    }
#pragma unroll
    for (int p = 0; p < 8; ++p) redp[p][tid] = bp[p];
    __syncthreads();
    for (int st = 128; st > 0; st >>= 1) {
        if (tid < st) {
#pragma unroll
            for (int p = 0; p < 8; ++p) redp[p][tid] += redp[p][tid + st];
        }
        __syncthreads();
    }
    float bv[8], bmax = -1e30f;
#pragma unroll
    for (int p = 0; p < 8; ++p) { bv[p] = redp[p][0]; bmax = fmaxf(bmax, bv[p]); }
    float esum = 0.f;
#pragma unroll
    for (int p = 0; p < 8; ++p) { bv[p] = __expf(bv[p] - bmax); esum += bv[p]; }
    float cinv = 1.f / esum;
    float sj2[4]; float part2 = 0.f;
#pragma unroll
    for (int jj = 0; jj < 4; ++jj) {
        float sv = 0.f;
#pragma unroll
        for (int p = 0; p < 8; ++p) sv += bv[p] * xrv[p][jj];
        sv *= cinv;
        sj2[jj] = sv;
        part2 += sv * sv;
    }
    __syncthreads();
    red[tid] = part2;
    __syncthreads();
    for (int st = 128; st > 0; st >>= 1) { if (tid < st) red[tid] += red[tid + st]; __syncthreads(); }
    float sq2 = red[0];
    float vfac2 = sq2 / ((1.f + sq2) * (sq2 + 1e-8f));
    float* outp = vjA + ((size_t)n * 64 + o) * TC_L + l0;
    *(float4*)outp = make_float4(vfac2*sj2[0], vfac2*sj2[1], vfac2*sj2[2], vfac2*sj2[3]);
}

// ---------------------------------------------------------------------------
// K6a (R5): DigitCaps partial GEMM. grid (kc=10, n=64, seg=5), 256 thr =
// 4 waves (o-quad each) x 64 d-lanes. No LDS, no barriers; shuffle-reduce.
// Segs 0-3: d in [seg*2048, +2048) from vjA; seg 4: d in [8192,8320) from xB.
// alpha/beta applied in K6b (segments are scale-homogeneous).
__global__ __launch_bounds__(256) void k_digit_gemm(
    const float* __restrict__ vjA, const float* __restrict__ xB,
    const float* __restrict__ W, float* __restrict__ upart)
{
    const int kc = blockIdx.x, n = blockIdx.y, seg = blockIdx.z;
    const int tid = threadIdx.x;
    const int lane = tid & 63;
    const int oq = tid >> 6;          // 0..3, wave-uniform
    const float* Wk = W + (size_t)kc * (TC_DCAT * 16);

    float acc[8][4] = {};
    if (seg < 4) {
        const float* xc = vjA + (size_t)n * 65536 + seg * 2048;   // [c][8192] slice
        const int d0 = seg * 2048;
#pragma unroll 2
        for (int it = 0; it < 32; ++it) {
            int dd = it * 64 + lane;
            float4 wv = *(const float4*)&Wk[(size_t)(d0 + dd) * 16 + oq * 4];
#pragma unroll
            for (int c = 0; c < 8; ++c) {
                float xv = xc[c * 8192 + dd];
                acc[c][0] = fmaf(wv.x, xv, acc[c][0]);
                acc[c][1] = fmaf(wv.y, xv, acc[c][1]);
                acc[c][2] = fmaf(wv.z, xv, acc[c][2]);
                acc[c][3] = fmaf(wv.w, xv, acc[c][3]);
            }
        }
    } else {
        const float* xc = xB + (size_t)n * 1024;                  // [c=8][128]
#pragma unroll
        for (int it = 0; it < 2; ++it) {
            int dd = it * 64 + lane;
            float4 wv = *(const float4*)&Wk[(size_t)(8192 + dd) * 16 + oq * 4];
#pragma unroll
            for (int c = 0; c < 8; ++c) {
                float xv = xc[c * 128 + dd];
                acc[c][0] = fmaf(wv.x, xv, acc[c][0]);
                acc[c][1] = fmaf(wv.y, xv, acc[c][1]);
                acc[c][2] = fmaf(wv.z, xv, acc[c][2]);
                acc[c][3] = fmaf(wv.w, xv, acc[c][3]);
            }
        }
    }

    // butterfly reduce over the 64 lanes of this wave
#pragma unroll
    for (int c = 0; c < 8; ++c) {
#pragma unroll
        for (int j = 0; j < 4; ++j) {
            float v = acc[c][j];
#pragma unroll
            for (int s = 32; s > 0; s >>= 1) v += __shfl_xor(v, s, 64);
            acc[c][j] = v;
        }
    }
    if (lane == 0) {
        float* up = upart + ((((size_t)n * TC_NCLS + kc) * 5 + seg) * 8) * 16;
#pragma unroll
        for (int c = 0; c < 8; ++c)
            *(float4*)&up[c * 16 + oq * 4] =
                make_float4(acc[c][0], acc[c][1], acc[c][2], acc[c][3]);
    }
}

// ---------------------------------------------------------------------------
// K6b (R5): sum 5 partials (alpha for 0-3, beta for 4) + routing -> out.
// grid (kc=10, n=64), 64 thr
__global__ __launch_bounds__(64) void k_digit_route(
    const float* __restrict__ upart, const float* __restrict__ alphap,
    const float* __restrict__ betap, float* __restrict__ out)
{
    const int kc = blockIdx.x, n = blockIdx.y;
    const int tid = threadIdx.x;
    const float alpha = alphap[0], beta = betap[0];
    __shared__ float ul[8][16];
    __shared__ float sjo[16];
    __shared__ float bc[8];
    __shared__ float fac[1];

    const float* up = upart + (((size_t)n * TC_NCLS + kc) * 5) * 128;
    for (int i = tid; i < 128; i += 64) {
        float sa = up[0 * 128 + i] + up[1 * 128 + i] + up[2 * 128 + i] + up[3 * 128 + i];
        ul[i >> 4][i & 15] = alpha * sa + beta * up[4 * 128 + i];
    }
    __syncthreads();

    // routing iter 1
    if (tid < 16) {
        float sv = 0.f;
#pragma unroll
        for (int c = 0; c < 8; ++c) sv += ul[c][tid];
        sjo[tid] = sv * 0.125f;
    }
    __syncthreads();
    if (tid == 0) {
        float sq = 0.f;
#pragma unroll
        for (int oo = 0; oo < 16; ++oo) sq += sjo[oo] * sjo[oo];
        fac[0] = sq / ((1.f + sq) * (sq + 1e-8f));
    }
    __syncthreads();
    if (tid < 8) {
        float vf = fac[0];
        float sv = 0.f;
#pragma unroll
        for (int oo = 0; oo < 16; ++oo) sv += ul[tid][oo] * (vf * sjo[oo]);
        bc[tid] = sv;
    }
    __syncthreads();
    // iter 2
    if (tid < 16) {
        float bmax = -1e30f;
#pragma unroll
        for (int c = 0; c < 8; ++c) bmax = fmaxf(bmax, bc[c]);
        float e[8]; float es = 0.f;
#pragma unroll
        for (int c = 0; c < 8; ++c) { e[c] = __expf(bc[c] - bmax); es += e[c]; }
        float inv = 1.f / es;
        float sv = 0.f;
#pragma unroll
        for (int c = 0; c < 8; ++c) sv += e[c] * inv * ul[c][tid];
        sjo[tid] = sv;
    }
    __syncthreads();
    if (tid == 0) {
        float sq = 0.f;
#pragma unroll
        for (int oo = 0; oo < 16; ++oo) sq += sjo[oo] * sjo[oo];
        fac[0] = sq / ((1.f + sq) * (sq + 1e-8f));
    }
    __syncthreads();
    if (tid < 16) {
        out[((size_t)n * TC_NCLS + kc) * 16 + tid] = fac[0] * sjo[tid];
    }
}

// ---------------------------------------------------------------------------
extern "C" void kernel_launch(void* const* d_in, const int* in_sizes, int n_in,
                              void* d_out, int out_size, void* d_ws, size_t ws_size,
                              hipStream_t stream) {
    const float* X   = (const float*)d_in[0];
    const float* w1  = (const float*)d_in[1];
    const float* w2  = (const float*)d_in[2];
    const float* wA  = (const float*)d_in[3];
    const float* bA  = (const float*)d_in[4];
    const float* wB  = (const float*)d_in[5];
    const float* bB  = (const float*)d_in[6];
    const float* wk  = (const float*)d_in[7];
    const float* bk  = (const float*)d_in[8];
    const float* Wd  = (const float*)d_in[9];
    const float* alphap = (const float*)d_in[10];
    const float* betap  = (const float*)d_in[11];
    float* out = (float*)d_out;

    float* ws  = (float*)d_ws;
    float* x   = ws;                     // [64][64][1024] = 4194304; reused as vjA
    float* xs  = ws + 4194304;           // [64][64][1024] = 4194304 (squashed in place)
    float* xbS = ws + 8388608;           // [64][8][8][128] = 65536
    float* xB  = ws + 8454144;           // [64][8][128]    = 65536 region
    float* xa  = ws + 8519680;           // [32][64][8][1024] = 16777216 (64MB, reused x2)
    float* vjA = x;                      // alias (x dead after k_cellB_conv)
    float* upart = xs;                   // [64][10][5][8][16] = 409600 (xs dead after cellA)

    const size_t need = (size_t)(8519680 + 16777216) * sizeof(float);
    const bool split = ws_size >= need;

    k_conv1<<<dim3(64, 64), 256, 0, stream>>>(X, w1, x);
    k_psim<<<dim3(8, 4, 64), 256, 0, stream>>>(x, w2, xs);
    k_squash_rows<<<dim3(4096), 256, 0, stream>>>(xs);
    k_cellB_conv<<<dim3(8, 64), 256, 0, stream>>>(x, wB, bB, wk, bk, xbS);
    k_routeB<<<dim3(8, 64), 128, 0, stream>>>(xbS, xB);
    if (split) {
        for (int g = 0; g < 2; ++g) {
            k_cellA_conv<<<dim3(16, 32), 256, 0, stream>>>(xs, wA, bA, xa, g * 32);
            k_cellA_route<<<dim3(64, 32), 256, 0, stream>>>(xa, vjA, g * 32);
        }
    } else {
        k_cellA<<<dim3(64, 64), 256, 0, stream>>>(xs, wA, bA, vjA);
    }
    // xs is dead from here on -> reuse as upart
    k_digit_gemm<<<dim3(10, 64, 5), 256, 0, stream>>>(vjA, xB, Wd, upart);
    k_digit_route<<<dim3(10, 64), 64, 0, stream>>>(upart, alphap, betap, out);
}

// Round 7
// 300.236 us; speedup vs baseline: 1.9658x; 1.0546x over previous
//
#include <hip/hip_runtime.h>

#define TC_L    1024
#define TC_K    64
#define TC_LN   128
#define TC_NCLS 10
#define TC_DCAT 8320

// ---------------------------------------------------------------------------
// K1: conv1  x[n,k,l] = sum_t w1[k,t] * X[n, l-4+t]   (pad 4)
// grid (k=64, n=64), 256 thr
__global__ __launch_bounds__(256) void k_conv1(
    const float* __restrict__ X, const float* __restrict__ w1, float* __restrict__ x)
{
    const int k = blockIdx.x, n = blockIdx.y;
    float w[9];
#pragma unroll
    for (int t = 0; t < 9; ++t) w[t] = w1[k * 9 + t];
    const float* xin = X + n * TC_L;
    float* out = x + (n * TC_K + k) * TC_L;
    for (int l = threadIdx.x; l < TC_L; l += 256) {
        float acc = 0.f;
#pragma unroll
        for (int t = 0; t < 9; ++t) {
            int idx = l - 4 + t;
            float v = (idx >= 0 && idx < TC_L) ? xin[idx] : 0.f;
            acc = fmaf(w[t], v, acc);
        }
        out[l] = acc;
    }
}

// ---------------------------------------------------------------------------
// K2 (R6): psi_m conv, 8 oc per thread (32 per block), weights re-laid in LDS
// as [(ic*5+t)][oc32] for b128 broadcast reads. grid (ocb=2, lcq=4, n=64),
// 256 thr = 64 lgrp x 4 ocg.
__global__ __launch_bounds__(256) void k_psim(
    const float* __restrict__ x, const float* __restrict__ w2, float* __restrict__ xs)
{
    const int ocb = blockIdx.x;       // 0..1 -> oc base = ocb*32
    const int lc  = blockIdx.y * 256;
    const int n   = blockIdx.z;
    __shared__ float wl[320 * 32];    // 40 KB: [(ic*5+t)][ocl]
    const int tid = threadIdx.x;
    for (int i = tid; i < 10240; i += 256) {
        int ocl = i & 31, r = i >> 5;             // r = ic*5 + t
        wl[r * 32 + ocl] = w2[(size_t)(ocb * 32 + ocl) * 320 + r];
    }
    __syncthreads();

    const int lgrp = tid & 63;
    const int ocg  = tid >> 6;        // 0..3, wave-uniform
    const int l0   = lgrp * 4;
    const bool lpad = (lc == 0) && (lgrp == 0);
    const bool rpad = (lc == 768) && (lgrp == 63);

    float acc[8][4] = {};
    const float* xn = x + (size_t)n * TC_K * TC_L;
#pragma unroll 2
    for (int ic = 0; ic < 64; ++ic) {
        const float* row = xn + ic * TC_L + lc;
        float4 va = *(const float4*)&row[l0];                    // l0..l0+3
        float2 vh = *(const float2*)&row[lpad ? l0 : (l0 - 2)];  // l0-2, l0-1
        float2 vb = *(const float2*)&row[l0 + 4];                // l0+4, l0+5
        if (lpad) { vh.x = 0.f; vh.y = 0.f; }
        if (rpad) { vb.x = 0.f; vb.y = 0.f; }
        float v[8] = {vh.x, vh.y, va.x, va.y, va.z, va.w, vb.x, vb.y};
        const float* wp = &wl[(ic * 5) * 32 + ocg * 8];
#pragma unroll
        for (int t = 0; t < 5; ++t) {
            float4 wa = *(const float4*)&wp[t * 32];
            float4 wb = *(const float4*)&wp[t * 32 + 4];
            float wq[8] = {wa.x, wa.y, wa.z, wa.w, wb.x, wb.y, wb.z, wb.w};
#pragma unroll
            for (int q = 0; q < 8; ++q) {
#pragma unroll
                for (int j = 0; j < 4; ++j)
                    acc[q][j] = fmaf(wq[q], v[j + t], acc[q][j]);
            }
        }
    }
#pragma unroll
    for (int q = 0; q < 8; ++q) {
        int oc = ocb * 32 + ocg * 8 + q;
        *(float4*)&xs[((size_t)n * TC_K + oc) * TC_L + lc + l0] =
            make_float4(acc[q][0], acc[q][1], acc[q][2], acc[q][3]);
    }
}

// ---------------------------------------------------------------------------
// K3: squash each row of 1024 in place
__global__ __launch_bounds__(256) void k_squash_rows(float* __restrict__ xs)
{
    const int row = blockIdx.x;
    float* p = xs + (size_t)row * TC_L;
    const int tid = threadIdx.x;
    float4 v = *(const float4*)&p[tid * 4];
    float part = v.x * v.x + v.y * v.y + v.z * v.z + v.w * v.w;
    __shared__ float red[256];
    red[tid] = part;
    __syncthreads();
    for (int s = 128; s > 0; s >>= 1) {
        if (tid < s) red[tid] += red[tid + s];
        __syncthreads();
    }
    float sq = red[0];
    float scale = sq / ((1.f + sq) * (sq + 1e-8f));
    v.x *= scale; v.y *= scale; v.z *= scale; v.w *= scale;
    *(float4*)&p[tid * 4] = v;
}

// ---------------------------------------------------------------------------
// K5a: Cell_B convs + bias + squash(last=128) -> xbS[n][j=8][s=8][128]
// grid (s=8, n=64), 256 thr
__global__ __launch_bounds__(256) void k_cellB_conv(
    const float* __restrict__ x, const float* __restrict__ wB, const float* __restrict__ bB,
    const float* __restrict__ wk, const float* __restrict__ bk, float* __restrict__ xbS)
{
    const int s = blockIdx.x;
    const int n = blockIdx.y;
    __shared__ float wBl[64 * 64];    // 16 KB
    __shared__ float wkl[8 * 320];    // 10 KB
    __shared__ float xb1[64][132];    // 33.8 KB  (2-elem zero halo each side)
    __shared__ float redq[8][33];
    const int tid = threadIdx.x;
    for (int i = tid; i < 4096; i += 256) wBl[i] = wB[i];
    for (int i = tid; i < 2560; i += 256) wkl[i] = wk[i];
    for (int i = tid; i < 64; i += 256) {
        xb1[i][0] = xb1[i][1] = xb1[i][130] = xb1[i][131] = 0.f;
    }
    __syncthreads();

    {
        const int t0  = (tid & 31) * 4;   // 0..124
        const int chg = tid >> 5;         // 0..7
        float acc[8][4] = {};
        const float* xbase = x + (size_t)n * TC_K * TC_L + s * TC_LN + t0;
        for (int k = 0; k < 64; ++k) {
            float4 xv = *(const float4*)&xbase[(size_t)k * TC_L];
            float v0 = xv.x, v1 = xv.y, v2 = xv.z, v3 = xv.w;
#pragma unroll
            for (int cc = 0; cc < 8; ++cc) {
                float w = wBl[(chg * 8 + cc) * 64 + k];
                acc[cc][0] = fmaf(w, v0, acc[cc][0]);
                acc[cc][1] = fmaf(w, v1, acc[cc][1]);
                acc[cc][2] = fmaf(w, v2, acc[cc][2]);
                acc[cc][3] = fmaf(w, v3, acc[cc][3]);
            }
        }
#pragma unroll
        for (int cc = 0; cc < 8; ++cc) {
            int ch = chg * 8 + cc;
            float b = bB[ch];
            xb1[ch][2 + t0 + 0] = acc[cc][0] + b;
            xb1[ch][2 + t0 + 1] = acc[cc][1] + b;
            xb1[ch][2 + t0 + 2] = acc[cc][2] + b;
            xb1[ch][2 + t0 + 3] = acc[cc][3] + b;
        }
    }
    __syncthreads();

    {
        const int t0 = (tid & 31) * 4;
        const int j  = tid >> 5;          // 0..7
        float acc[4] = {};
        for (int ch = 0; ch < 64; ++ch) {
            float4 va = *(const float4*)&xb1[ch][t0];
            float4 vb = *(const float4*)&xb1[ch][t0 + 4];
            float v[8] = {va.x, va.y, va.z, va.w, vb.x, vb.y, vb.z, vb.w};
            const float* wp = &wkl[j * 320 + ch * 5];
#pragma unroll
            for (int dw = 0; dw < 5; ++dw) {
                float w = wp[dw];
#pragma unroll
                for (int q = 0; q < 4; ++q) acc[q] = fmaf(w, v[q + dw], acc[q]);
            }
        }
        float b = bk[j];
#pragma unroll
        for (int q = 0; q < 4; ++q) acc[q] += b;
        float part = acc[0]*acc[0] + acc[1]*acc[1] + acc[2]*acc[2] + acc[3]*acc[3];
        redq[j][tid & 31] = part;
        __syncthreads();
        for (int st = 16; st > 0; st >>= 1) {
            if ((tid & 31) < st) redq[j][tid & 31] += redq[j][(tid & 31) + st];
            __syncthreads();
        }
        float sq = redq[j][0];
        float scale = sq / ((1.f + sq) * (sq + 1e-8f));
        float* outp = xbS + (((size_t)n * 8 + j) * 8 + s) * TC_LN + t0;
        *(float4*)outp = make_float4(acc[0]*scale, acc[1]*scale, acc[2]*scale, acc[3]*scale);
    }
}

// ---------------------------------------------------------------------------
// K5b: routing over s for Cell_B -> xB[n][j][t]
__global__ __launch_bounds__(128) void k_routeB(
    const float* __restrict__ xbS, float* __restrict__ xB)
{
    const int j = blockIdx.x, n = blockIdx.y;
    const int t = threadIdx.x;
    float xv[8];
    const float* base = xbS + ((size_t)n * 8 + j) * 8 * TC_LN;
#pragma unroll
    for (int s = 0; s < 8; ++s) xv[s] = base[s * TC_LN + t];

    __shared__ float red[128];
    __shared__ float redp[8][129];

    float sj = 0.f;
#pragma unroll
    for (int s = 0; s < 8; ++s) sj += xv[s];
    sj *= 0.125f;
    red[t] = sj * sj;
    __syncthreads();
    for (int st = 64; st > 0; st >>= 1) { if (t < st) red[t] += red[t + st]; __syncthreads(); }
    float sq = red[0];
    float vfac = sq / ((1.f + sq) * (sq + 1e-8f));
    float vj = vfac * sj;
#pragma unroll
    for (int s = 0; s < 8; ++s) redp[s][t] = xv[s] * vj;
    __syncthreads();
    for (int st = 64; st > 0; st >>= 1) {
        if (t < st) {
#pragma unroll
            for (int s = 0; s < 8; ++s) redp[s][t] += redp[s][t + st];
        }
        __syncthreads();
    }
    float bv[8], bmax = -1e30f;
#pragma unroll
    for (int s = 0; s < 8; ++s) { bv[s] = redp[s][0]; bmax = fmaxf(bmax, bv[s]); }
    float esum = 0.f;
#pragma unroll
    for (int s = 0; s < 8; ++s) { bv[s] = __expf(bv[s] - bmax); esum += bv[s]; }
    float cinv = 1.f / esum;
    float sj2 = 0.f;
#pragma unroll
    for (int s = 0; s < 8; ++s) sj2 += bv[s] * xv[s];
    sj2 *= cinv;
    __syncthreads();
    red[t] = sj2 * sj2;
    __syncthreads();
    for (int st = 64; st > 0; st >>= 1) { if (t < st) red[t] += red[t + st]; __syncthreads(); }
    float sq2 = red[0];
    float vfac2 = sq2 / ((1.f + sq2) * (sq2 + 1e-8f));
    xB[((size_t)n * 8 + j) * TC_LN + t] = vfac2 * sj2;
}

// ---------------------------------------------------------------------------
// K4a: Cell_A conv for all 64 o, one l-chunk of 64, one n.
// grid (16 chunks, 32 n), 256 thr = 16 l-strips x 16 o-groups(4 o each)
__global__ __launch_bounds__(256) void k_cellA_conv(
    const float* __restrict__ xs, const float* __restrict__ wA, const float* __restrict__ bA,
    float* __restrict__ xa, int n0)
{
    const int lc = blockIdx.x * 64;
    const int nrel = blockIdx.y;
    const int n = n0 + nrel;
    const int tid = threadIdx.x;
    __shared__ float xl[64][68];      // cols c=0..65 <-> global l = lc + c - 1
    __shared__ float wl[64 * 24];
    __shared__ float bl[64];
    for (int i = tid; i < 64 * 24; i += 256) wl[i] = wA[i];
    if (tid < 64) bl[tid] = bA[tid];
    const float* xsn = xs + (size_t)n * (TC_K * TC_L);
    for (int i = tid; i < 64 * 66; i += 256) {
        int k = i / 66, c = i - k * 66;
        int gl = lc + c - 1;
        xl[k][c] = (gl >= 0 && gl < TC_L) ? xsn[k * TC_L + gl] : 0.f;
    }
    __syncthreads();

    const int strip = tid & 15;       // l0 = strip*4
    const int g = tid >> 4;           // o = g*4 + oi
    const int l0 = strip * 4;
    float* xab = xa + (size_t)nrel * 64 * 8192;   // [o][p][1024]

#pragma unroll 1
    for (int oi = 0; oi < 4; ++oi) {
        const int o = g * 4 + oi;
        float w[24];
#pragma unroll
        for (int i = 0; i < 24; ++i) w[i] = wl[o * 24 + i];
        const float bias = bl[o];
#pragma unroll
        for (int p = 0; p < 8; ++p) {
            float a0 = bias, a1 = bias, a2 = bias, a3 = bias;
#pragma unroll
            for (int dh = 0; dh < 8; ++dh) {
                const float* row = &xl[p * 8 + dh][l0];
                float4 va = *(const float4*)row;
                float2 vb = *(const float2*)(row + 4);
                float w0 = w[dh * 3], w1 = w[dh * 3 + 1], w2 = w[dh * 3 + 2];
                a0 = fmaf(w0, va.x, a0); a0 = fmaf(w1, va.y, a0); a0 = fmaf(w2, va.z, a0);
                a1 = fmaf(w0, va.y, a1); a1 = fmaf(w1, va.z, a1); a1 = fmaf(w2, va.w, a1);
                a2 = fmaf(w0, va.z, a2); a2 = fmaf(w1, va.w, a2); a2 = fmaf(w2, vb.x, a2);
                a3 = fmaf(w0, va.w, a3); a3 = fmaf(w1, vb.x, a3); a3 = fmaf(w2, vb.y, a3);
            }
            *(float4*)&xab[(size_t)o * 8192 + p * TC_L + lc + l0] = make_float4(a0, a1, a2, a3);
        }
    }
}

// ---------------------------------------------------------------------------
// K4b: routing over p from xa (contiguous 32KB per (n,o)), coalesced loads.
// grid (o=64, 32 n), 256 thr
__global__ __launch_bounds__(256) void k_cellA_route(
    const float* __restrict__ xa, float* __restrict__ vjA, int n0)
{
    const int o = blockIdx.x;
    const int nrel = blockIdx.y;
    const int n = n0 + nrel;
    const int tid = threadIdx.x;
    const int l0 = tid * 4;
    const float* base = xa + ((size_t)nrel * 64 + o) * 8192;

    float xrv[8][4];
#pragma unroll
    for (int p = 0; p < 8; ++p) {
        float4 v = *(const float4*)&base[p * TC_L + l0];
        xrv[p][0] = v.x; xrv[p][1] = v.y; xrv[p][2] = v.z; xrv[p][3] = v.w;
    }

    __shared__ float red[256];
    __shared__ float redp[8][257];

    float sjv[4];
    float part = 0.f;
#pragma unroll
    for (int jj = 0; jj < 4; ++jj) {
        float sv = 0.f;
#pragma unroll
        for (int p = 0; p < 8; ++p) sv += xrv[p][jj];
        sv *= 0.125f;
        sjv[jj] = sv;
        part += sv * sv;
    }
    red[tid] = part;
    __syncthreads();
    for (int st = 128; st > 0; st >>= 1) { if (tid < st) red[tid] += red[tid + st]; __syncthreads(); }
    float sq = red[0];
    float vfac = sq / ((1.f + sq) * (sq + 1e-8f));
    float bp[8] = {};
#pragma unroll
    for (int jj = 0; jj < 4; ++jj) {
        float vj = vfac * sjv[jj];
#pragma unroll
        for (int p = 0; p < 8; ++p) bp[p] += xrv[p][jj] * vj;
    }
#pragma unroll
    for (int p = 0; p < 8; ++p) redp[p][tid] = bp[p];
    __syncthreads();
    for (int st = 128; st > 0; st >>= 1) {
        if (tid < st) {
#pragma unroll
            for (int p = 0; p < 8; ++p) redp[p][tid] += redp[p][tid + st];
        }
        __syncthreads();
    }
    float bv[8], bmax = -1e30f;
#pragma unroll
    for (int p = 0; p < 8; ++p) { bv[p] = redp[p][0]; bmax = fmaxf(bmax, bv[p]); }
    float esum = 0.f;
#pragma unroll
    for (int p = 0; p < 8; ++p) { bv[p] = __expf(bv[p] - bmax); esum += bv[p]; }
    float cinv = 1.f / esum;
    float sj2[4]; float part2 = 0.f;
#pragma unroll
    for (int jj = 0; jj < 4; ++jj) {
        float sv = 0.f;
#pragma unroll
        for (int p = 0; p < 8; ++p) sv += bv[p] * xrv[p][jj];
        sv *= cinv;
        sj2[jj] = sv;
        part2 += sv * sv;
    }
    __syncthreads();
    red[tid] = part2;
    __syncthreads();
    for (int st = 128; st > 0; st >>= 1) { if (tid < st) red[tid] += red[tid + st]; __syncthreads(); }
    float sq2 = red[0];
    float vfac2 = sq2 / ((1.f + sq2) * (sq2 + 1e-8f));
    float* outp = vjA + ((size_t)n * 64 + o) * TC_L + l0;
    *(float4*)outp = make_float4(vfac2*sj2[0], vfac2*sj2[1], vfac2*sj2[2], vfac2*sj2[3]);
}

// ---------------------------------------------------------------------------
// K4 (fallback): fused Cell_A — used only if ws too small for xa.
__global__ __launch_bounds__(256, 4) void k_cellA(
    const float* __restrict__ xs, const float* __restrict__ wA, const float* __restrict__ bA,
    float* __restrict__ vjA)
{
    const int o = blockIdx.x;
    const int n = blockIdx.y;
    const int tid = threadIdx.x;
    const int l0 = tid * 4;

    float w[24];
#pragma unroll
    for (int i = 0; i < 24; ++i) w[i] = wA[o * 24 + i];
    const float bias = bA[o];

    const float* xsn = xs + (size_t)n * TC_K * TC_L;
    float xrv[8][4];
#pragma unroll 1
    for (int p = 0; p < 8; ++p) {
        float a0 = bias, a1 = bias, a2 = bias, a3 = bias;
#pragma unroll
        for (int dh = 0; dh < 8; ++dh) {
            const float* row = xsn + (p * 8 + dh) * TC_L;
            float4 vm = *(const float4*)&row[l0];
            float vl = (l0 > 0) ? row[l0 - 1] : 0.f;
            float vr = (l0 + 4 < TC_L) ? row[l0 + 4] : 0.f;
            float w0 = w[dh * 3 + 0], w1 = w[dh * 3 + 1], w2 = w[dh * 3 + 2];
            a0 = fmaf(w0, vl,   a0); a0 = fmaf(w1, vm.x, a0); a0 = fmaf(w2, vm.y, a0);
            a1 = fmaf(w0, vm.x, a1); a1 = fmaf(w1, vm.y, a1); a1 = fmaf(w2, vm.z, a1);
            a2 = fmaf(w0, vm.y, a2); a2 = fmaf(w1, vm.z, a2); a2 = fmaf(w2, vm.w, a2);
            a3 = fmaf(w0, vm.z, a3); a3 = fmaf(w1, vm.w, a3); a3 = fmaf(w2, vr,   a3);
        }
        xrv[p][0] = a0; xrv[p][1] = a1; xrv[p][2] = a2; xrv[p][3] = a3;
    }

    __shared__ float red[256];
    __shared__ float redp[8][257];

    float sjv[4];
    float part = 0.f;
#pragma unroll
    for (int jj = 0; jj < 4; ++jj) {
        float sv = 0.f;
#pragma unroll
        for (int p = 0; p < 8; ++p) sv += xrv[p][jj];
        sv *= 0.125f;
        sjv[jj] = sv;
        part += sv * sv;
    }
    red[tid] = part;
    __syncthreads();
    for (int st = 128; st > 0; st >>= 1) { if (tid < st) red[tid] += red[tid + st]; __syncthreads(); }
    float sq = red[0];
    float vfac = sq / ((1.f + sq) * (sq + 1e-8f));
    float bp[8] = {};
#pragma unroll
    for (int jj = 0; jj < 4; ++jj) {
        float vj = vfac * sjv[jj];
#pragma unroll
        for (int p = 0; p < 8; ++p) bp[p] += xrv[p][jj] * vj;
    }
#pragma unroll
    for (int p = 0; p < 8; ++p) redp[p][tid] = bp[p];
    __syncthreads();
    for (int st = 128; st > 0; st >>= 1) {
        if (tid < st) {
#pragma unroll
            for (int p = 0; p < 8; ++p) redp[p][tid] += redp[p][tid + st];
        }
        __syncthreads();
    }
    float bv[8], bmax = -1e30f;
#pragma unroll
    for (int p = 0; p < 8; ++p) { bv[p] = redp[p][0]; bmax = fmaxf(bmax, bv[p]); }
    float esum = 0.f;
#pragma unroll
    for (int p = 0; p < 8; ++p) { bv[p] = __expf(bv[p] - bmax); esum += bv[p]; }
    float cinv = 1.f / esum;
    float sj2[4]; float part2 = 0.f;
#pragma unroll
    for (int jj = 0; jj < 4; ++jj) {
        float sv = 0.f;
#pragma unroll
        for (int p = 0; p < 8; ++p) sv += bv[p] * xrv[p][jj];
        sv *= cinv;
        sj2[jj] = sv;
        part2 += sv * sv;
    }
    __syncthreads();
    red[tid] = part2;
    __syncthreads();
    for (int st = 128; st > 0; st >>= 1) { if (tid < st) red[tid] += red[tid + st]; __syncthreads(); }
    float sq2 = red[0];
    float vfac2 = sq2 / ((1.f + sq2) * (sq2 + 1e-8f));
    float* outp = vjA + ((size_t)n * 64 + o) * TC_L + l0;
    *(float4*)outp = make_float4(vfac2*sj2[0], vfac2*sj2[1], vfac2*sj2[2], vfac2*sj2[3]);
}

// ---------------------------------------------------------------------------
// K6a: DigitCaps partial GEMM. grid (kc=10, n=64, seg=5), 256 thr =
// 4 waves (o-quad each) x 64 d-lanes. No LDS, no barriers; shuffle-reduce.
__global__ __launch_bounds__(256) void k_digit_gemm(
    const float* __restrict__ vjA, const float* __restrict__ xB,
    const float* __restrict__ W, float* __restrict__ upart)
{
    const int kc = blockIdx.x, n = blockIdx.y, seg = blockIdx.z;
    const int tid = threadIdx.x;
    const int lane = tid & 63;
    const int oq = tid >> 6;          // 0..3, wave-uniform
    const float* Wk = W + (size_t)kc * (TC_DCAT * 16);

    float acc[8][4] = {};
    if (seg < 4) {
        const float* xc = vjA + (size_t)n * 65536 + seg * 2048;   // [c][8192] slice
        const int d0 = seg * 2048;
#pragma unroll 2
        for (int it = 0; it < 32; ++it) {
            int dd = it * 64 + lane;
            float4 wv = *(const float4*)&Wk[(size_t)(d0 + dd) * 16 + oq * 4];
#pragma unroll
            for (int c = 0; c < 8; ++c) {
                float xv = xc[c * 8192 + dd];
                acc[c][0] = fmaf(wv.x, xv, acc[c][0]);
                acc[c][1] = fmaf(wv.y, xv, acc[c][1]);
                acc[c][2] = fmaf(wv.z, xv, acc[c][2]);
                acc[c][3] = fmaf(wv.w, xv, acc[c][3]);
            }
        }
    } else {
        const float* xc = xB + (size_t)n * 1024;                  // [c=8][128]
#pragma unroll
        for (int it = 0; it < 2; ++it) {
            int dd = it * 64 + lane;
            float4 wv = *(const float4*)&Wk[(size_t)(8192 + dd) * 16 + oq * 4];
#pragma unroll
            for (int c = 0; c < 8; ++c) {
                float xv = xc[c * 128 + dd];
                acc[c][0] = fmaf(wv.x, xv, acc[c][0]);
                acc[c][1] = fmaf(wv.y, xv, acc[c][1]);
                acc[c][2] = fmaf(wv.z, xv, acc[c][2]);
                acc[c][3] = fmaf(wv.w, xv, acc[c][3]);
            }
        }
    }

#pragma unroll
    for (int c = 0; c < 8; ++c) {
#pragma unroll
        for (int j = 0; j < 4; ++j) {
            float v = acc[c][j];
#pragma unroll
            for (int s = 32; s > 0; s >>= 1) v += __shfl_xor(v, s, 64);
            acc[c][j] = v;
        }
    }
    if (lane == 0) {
        float* up = upart + ((((size_t)n * TC_NCLS + kc) * 5 + seg) * 8) * 16;
#pragma unroll
        for (int c = 0; c < 8; ++c)
            *(float4*)&up[c * 16 + oq * 4] =
                make_float4(acc[c][0], acc[c][1], acc[c][2], acc[c][3]);
    }
}

// ---------------------------------------------------------------------------
// K6b: sum 5 partials (alpha for 0-3, beta for 4) + routing -> out.
// grid (kc=10, n=64), 64 thr
__global__ __launch_bounds__(64) void k_digit_route(
    const float* __restrict__ upart, const float* __restrict__ alphap,
    const float* __restrict__ betap, float* __restrict__ out)
{
    const int kc = blockIdx.x, n = blockIdx.y;
    const int tid = threadIdx.x;
    const float alpha = alphap[0], beta = betap[0];
    __shared__ float ul[8][16];
    __shared__ float sjo[16];
    __shared__ float bc[8];
    __shared__ float fac[1];

    const float* up = upart + (((size_t)n * TC_NCLS + kc) * 5) * 128;
    for (int i = tid; i < 128; i += 64) {
        float sa = up[0 * 128 + i] + up[1 * 128 + i] + up[2 * 128 + i] + up[3 * 128 + i];
        ul[i >> 4][i & 15] = alpha * sa + beta * up[4 * 128 + i];
    }
    __syncthreads();

    // routing iter 1
    if (tid < 16) {
        float sv = 0.f;
#pragma unroll
        for (int c = 0; c < 8; ++c) sv += ul[c][tid];
        sjo[tid] = sv * 0.125f;
    }
    __syncthreads();
    if (tid == 0) {
        float sq = 0.f;
#pragma unroll
        for (int oo = 0; oo < 16; ++oo) sq += sjo[oo] * sjo[oo];
        fac[0] = sq / ((1.f + sq) * (sq + 1e-8f));
    }
    __syncthreads();
    if (tid < 8) {
        float vf = fac[0];
        float sv = 0.f;
#pragma unroll
        for (int oo = 0; oo < 16; ++oo) sv += ul[tid][oo] * (vf * sjo[oo]);
        bc[tid] = sv;
    }
    __syncthreads();
    // iter 2
    if (tid < 16) {
        float bmax = -1e30f;
#pragma unroll
        for (int c = 0; c < 8; ++c) bmax = fmaxf(bmax, bc[c]);
        float e[8]; float es = 0.f;
#pragma unroll
        for (int c = 0; c < 8; ++c) { e[c] = __expf(bc[c] - bmax); es += e[c]; }
        float inv = 1.f / es;
        float sv = 0.f;
#pragma unroll
        for (int c = 0; c < 8; ++c) sv += e[c] * inv * ul[c][tid];
        sjo[tid] = sv;
    }
    __syncthreads();
    if (tid == 0) {
        float sq = 0.f;
#pragma unroll
        for (int oo = 0; oo < 16; ++oo) sq += sjo[oo] * sjo[oo];
        fac[0] = sq / ((1.f + sq) * (sq + 1e-8f));
    }
    __syncthreads();
    if (tid < 16) {
        out[((size_t)n * TC_NCLS + kc) * 16 + tid] = fac[0] * sjo[tid];
    }
}

// ---------------------------------------------------------------------------
extern "C" void kernel_launch(void* const* d_in, const int* in_sizes, int n_in,
                              void* d_out, int out_size, void* d_ws, size_t ws_size,
                              hipStream_t stream) {
    const float* X   = (const float*)d_in[0];
    const float* w1  = (const float*)d_in[1];
    const float* w2  = (const float*)d_in[2];
    const float* wA  = (const float*)d_in[3];
    const float* bA  = (const float*)d_in[4];
    const float* wB  = (const float*)d_in[5];
    const float* bB  = (const float*)d_in[6];
    const float* wk  = (const float*)d_in[7];
    const float* bk  = (const float*)d_in[8];
    const float* Wd  = (const float*)d_in[9];
    const float* alphap = (const float*)d_in[10];
    const float* betap  = (const float*)d_in[11];
    float* out = (float*)d_out;

    float* ws  = (float*)d_ws;
    float* x   = ws;                     // [64][64][1024] = 4194304; reused as vjA
    float* xs  = ws + 4194304;           // [64][64][1024] = 4194304 (squashed in place)
    float* xbS = ws + 8388608;           // [64][8][8][128] = 65536
    float* xB  = ws + 8454144;           // [64][8][128]    = 65536 region
    float* xa  = ws + 8519680;           // [32][64][8][1024] = 16777216 (64MB, reused x2)
    float* vjA = x;                      // alias (x dead after k_cellB_conv)
    float* upart = xs;                   // [64][10][5][8][16] = 409600 (xs dead after cellA)

    const size_t need = (size_t)(8519680 + 16777216) * sizeof(float);
    const bool split = ws_size >= need;

    k_conv1<<<dim3(64, 64), 256, 0, stream>>>(X, w1, x);
    k_psim<<<dim3(2, 4, 64), 256, 0, stream>>>(x, w2, xs);
    k_squash_rows<<<dim3(4096), 256, 0, stream>>>(xs);
    k_cellB_conv<<<dim3(8, 64), 256, 0, stream>>>(x, wB, bB, wk, bk, xbS);
    k_routeB<<<dim3(8, 64), 128, 0, stream>>>(xbS, xB);
    if (split) {
        for (int g = 0; g < 2; ++g) {
            k_cellA_conv<<<dim3(16, 32), 256, 0, stream>>>(xs, wA, bA, xa, g * 32);
            k_cellA_route<<<dim3(64, 32), 256, 0, stream>>>(xa, vjA, g * 32);
        }
    } else {
        k_cellA<<<dim3(64, 64), 256, 0, stream>>>(xs, wA, bA, vjA);
    }
    // xs is dead from here on -> reuse as upart
    k_digit_gemm<<<dim3(10, 64, 5), 256, 0, stream>>>(vjA, xB, Wd, upart);
    k_digit_route<<<dim3(10, 64), 64, 0, stream>>>(upart, alphap, betap, out);
}